// Round 10
// baseline (186.582 us; speedup 1.0000x reference)
//
#include <hip/hip_runtime.h>
#include <hip/hip_bf16.h>
#include <math.h>

#define DEVINL __device__ __forceinline__

typedef __attribute__((ext_vector_type(8))) short bf16x8;
typedef __attribute__((ext_vector_type(8))) unsigned short u16x8;
typedef __attribute__((ext_vector_type(4))) float f32x4;

DEVINL float lrelu(float x) { return x > 0.f ? x : 0.2f * x; }

DEVINL unsigned short f2bf_rne(float f) {
    unsigned u = __float_as_uint(f);
    unsigned r = u + 0x7fff + ((u >> 16) & 1);
    return (unsigned short)(r >> 16);
}
DEVINL float bf2f(unsigned short h) { return __uint_as_float(((unsigned)h) << 16); }

DEVINL void gload_lds16(const void* g, void* l) {
    __builtin_amdgcn_global_load_lds(
        (const __attribute__((address_space(1))) void*)g,
        (__attribute__((address_space(3))) void*)l, 16, 0, 0);
}

// ---------------- CSR build ----------------

__global__ void build_edges(const int* __restrict__ ei, int E, int N,
                            int* __restrict__ src, int* __restrict__ dst,
                            int* __restrict__ counts) {
    int e = blockIdx.x * 256 + threadIdx.x;
    int ET = E + N;
    if (e >= ET) return;
    int s, d;
    if (e < E) { s = ei[e]; d = ei[E + e]; }
    else       { s = d = e - E; }
    s = min(max(s, 0), N - 1);
    d = min(max(d, 0), N - 1);
    src[e] = s;
    dst[e] = d;
    atomicAdd(&counts[d], 1);
}

__global__ void scan_offsets(const int* __restrict__ counts, int* __restrict__ offsets, int N) {
    const int T = 1024;
    __shared__ int sums[T];
    int t = threadIdx.x;
    int chunk = (N + T - 1) / T;
    int base = t * chunk;
    int local[16];
    int s = 0;
    for (int i = 0; i < chunk; ++i) {
        int v = (base + i < N) ? counts[base + i] : 0;
        local[i] = s;
        s += v;
    }
    sums[t] = s;
    __syncthreads();
    for (int d = 1; d < T; d <<= 1) {
        int v = (t >= d) ? sums[t - d] : 0;
        __syncthreads();
        sums[t] += v;
        __syncthreads();
    }
    int excl = (t == 0) ? 0 : sums[t - 1];
    for (int i = 0; i < chunk; ++i)
        if (base + i < N) offsets[base + i] = excl + local[i];
    if (t == T - 1) offsets[N] = excl + s;
}

__global__ void fill_eids(const int* __restrict__ src, const int* __restrict__ dst,
                          const int* __restrict__ offsets,
                          int* __restrict__ cursor, int* __restrict__ esrc, int ET) {
    int e = blockIdx.x * 256 + threadIdx.x;
    if (e >= ET) return;
    int d = dst[e];
    int pos = offsets[d] + atomicAdd(&cursor[d], 1);
    esrc[pos] = src[e];
}

// ---------------- f32 -> hi bf16 (RNE), zero-padded rows >= M ----------------
__global__ void conv_hi(const float* __restrict__ x, unsigned short* __restrict__ hi,
                        int M, int log2K, int total4) {
    int i = blockIdx.x * 256 + threadIdx.x;
    if (i >= total4) return;
    int e = i * 4;
    int row = e >> log2K;
    ushort4 vh = make_ushort4(0, 0, 0, 0);
    if (row < M) {
        float4 v = *(const float4*)&x[e];
        vh = make_ushort4(f2bf_rne(v.x), f2bf_rne(v.y), f2bf_rne(v.z), f2bf_rne(v.w));
    }
    *(ushort4*)&hi[e] = vh;
}

// ---------------- W[K][Nout] f32 -> BT[Nout][K] hi bf16 ----------------
__global__ void thi(const float* __restrict__ W, unsigned short* __restrict__ BTh,
                    int K, int Nout) {
    __shared__ float tile[32][33];
    int n0 = blockIdx.x * 32, k0 = blockIdx.y * 32;
    int tx = threadIdx.x, ty = threadIdx.y;
#pragma unroll
    for (int i = 0; i < 4; ++i)
        tile[ty + 8 * i][tx] = W[(size_t)(k0 + ty + 8 * i) * Nout + n0 + tx];
    __syncthreads();
#pragma unroll
    for (int i = 0; i < 4; ++i) {
        int r = ty + 8 * i;
        BTh[(size_t)(n0 + r) * K + k0 + tx] = f2bf_rne(tile[tx][r]);
    }
}

// ---------------- bf16 MFMA GEMM: C[M][Nout] = A[M2][K] @ BT[Nout][K]^T ----------------
// 128x128 tile, BK=64, 4 waves (2x2), 16x16x32 bf16 MFMA, T1 bijective XCD swizzle.
template <int TERMS, bool OUTBF16>
__global__ __launch_bounds__(256) void gemm_mfma(
    const unsigned short* __restrict__ Ah, const unsigned short* __restrict__ Al,
    const unsigned short* __restrict__ Bh,
    float* __restrict__ Cf, unsigned short* __restrict__ Cb,
    int M, int Nout, int K) {
    constexpr int BOFF = (TERMS == 2) ? 32768 : 16384;
    __shared__ __align__(16) char lds[BOFF + 16384];
    const int t = threadIdx.x;
    const int L = t & 63, w = t >> 6;
    const int wm = w & 1, wn = w >> 1;
    const int nwg = gridDim.x * gridDim.y;
    int orig = blockIdx.y * gridDim.x + blockIdx.x;
    int q = nwg >> 3, rr = nwg & 7;
    int xcd = orig & 7, pos = orig >> 3;
    int wg = (xcd < rr ? xcd * (q + 1) : rr * (q + 1) + (xcd - rr) * q) + pos;
    const int bm = (wg / gridDim.x) * 128, bn = (wg % gridDim.x) * 128;
    const size_t strideA = (size_t)K * 2;

    const f32x4 vzero = {0.f, 0.f, 0.f, 0.f};
    f32x4 acc[4][4];
#pragma unroll
    for (int i = 0; i < 4; ++i)
#pragma unroll
        for (int j = 0; j < 4; ++j) acc[i][j] = vzero;

    for (int k0 = 0; k0 < K; k0 += 64) {
#pragma unroll
        for (int i = 0; i < 4; ++i) {
            int slot = i * 256 + t;
            int offs = slot * 16;
            int r = offs >> 7;
            int cb = (offs & 127) ^ ((r & 7) << 4);
            size_t gofs = (size_t)r * strideA + (size_t)k0 * 2 + cb;
            gload_lds16((const char*)Ah + (size_t)bm * strideA + gofs, lds + offs);
            if constexpr (TERMS == 2)
                gload_lds16((const char*)Al + (size_t)bm * strideA + gofs, lds + 16384 + offs);
            gload_lds16((const char*)Bh + (size_t)bn * strideA + gofs, lds + BOFF + offs);
        }
        __syncthreads();
#pragma unroll
        for (int kf = 0; kf < 2; ++kf) {
            const int kb = kf * 64 + ((L >> 4) * 16);
            bf16x8 ah[4], al[4], bh[4];
#pragma unroll
            for (int mi = 0; mi < 4; ++mi) {
                int r = wm * 64 + mi * 16 + (L & 15);
                int off = r * 128 + (kb ^ ((r & 7) << 4));
                ah[mi] = *(const bf16x8*)(lds + off);
                if constexpr (TERMS == 2) al[mi] = *(const bf16x8*)(lds + 16384 + off);
            }
#pragma unroll
            for (int ni = 0; ni < 4; ++ni) {
                int r = wn * 64 + ni * 16 + (L & 15);
                int off = r * 128 + (kb ^ ((r & 7) << 4));
                bh[ni] = *(const bf16x8*)(lds + BOFF + off);
            }
#pragma unroll
            for (int mi = 0; mi < 4; ++mi)
#pragma unroll
                for (int ni = 0; ni < 4; ++ni) {
                    acc[mi][ni] = __builtin_amdgcn_mfma_f32_16x16x32_bf16(ah[mi], bh[ni], acc[mi][ni], 0, 0, 0);
                    if constexpr (TERMS == 2)
                        acc[mi][ni] = __builtin_amdgcn_mfma_f32_16x16x32_bf16(al[mi], bh[ni], acc[mi][ni], 0, 0, 0);
                }
        }
        __syncthreads();
    }
    const int colBase = bn + wn * 64 + (L & 15);
#pragma unroll
    for (int mi = 0; mi < 4; ++mi) {
        int row0 = bm + wm * 64 + mi * 16 + (L >> 4) * 4;
#pragma unroll
        for (int j = 0; j < 4; ++j) {
            int row = row0 + j;
            if (row < M) {
#pragma unroll
                for (int ni = 0; ni < 4; ++ni) {
                    if constexpr (OUTBF16)
                        Cb[(size_t)row * Nout + colBase + ni * 16] = f2bf_rne(acc[mi][ni][j]);
                    else
                        Cf[(size_t)row * Nout + colBase + ni * 16] = acc[mi][ni][j];
                }
            }
        }
    }
}

// ---------------- layer-1 fused aggregate: block(128) per node ----------------
// Wave w (of 2) covers heads 2w,2w+1: its 64 lanes read ONE contiguous 1KB
// (lane-stride 16B, each cache line requested exactly once — round-4 access
// shape). Logit reduce = 5 shfl within 32-lane half; head-merge via 4KB LDS;
// fused bias + lrelu + hi/lo bf16 split write. Rows >= N zero-padded.
__global__ __launch_bounds__(128) void agg1(const unsigned short* __restrict__ xlr,  // [M2][2048]
                                            const float* __restrict__ att,           // [4][256]
                                            const int* __restrict__ offsets,
                                            const int* __restrict__ esrc,
                                            const float* __restrict__ bias,          // [256]
                                            unsigned short* __restrict__ outH,
                                            unsigned short* __restrict__ outL,
                                            int N) {
    __shared__ float accLds[4][256];
    const int t = threadIdx.x;
    const int wv = t >> 6, lane = t & 63;
    const int n = blockIdx.x;

    if (n >= N) {   // zero-pad rows for downstream MFMA GEMM
        int c = t * 2;
        *(ushort2*)&outH[(size_t)n * 256 + c] = make_ushort2(0, 0);
        *(ushort2*)&outL[(size_t)n * 256 + c] = make_ushort2(0, 0);
        return;
    }

    const int eoff = 512 * wv + lane * 8;   // element offset within xl row (0..1023)
    const int h = eoff >> 8;                // head 0..3
    const int gl = lane & 31;               // 8-channel group within head

    float a[8];
    {
        const float* pa = att + h * 256 + gl * 8;
        float4 a0 = *(const float4*)pa, a1 = *(const float4*)(pa + 4);
        a[0] = a0.x; a[1] = a0.y; a[2] = a0.z; a[3] = a0.w;
        a[4] = a1.x; a[5] = a1.y; a[6] = a1.z; a[7] = a1.w;
    }
    float r[8];
    {
        u16x8 u = *(const u16x8*)(xlr + (size_t)n * 2048 + 1024 + eoff);
#pragma unroll
        for (int v = 0; v < 8; ++v) r[v] = bf2f(u[v]);
    }
    int o0 = offsets[n];
    int deg = offsets[n + 1] - o0;

    float acc[8];
#pragma unroll
    for (int v = 0; v < 8; ++v) acc[v] = 0.f;
    float s = 0.f;

    for (int j = 0; j < deg; j += 2) {
        int e0 = esrc[o0 + j];
        bool has1 = (j + 1) < deg;
        int e1 = esrc[o0 + (has1 ? j + 1 : j)];
        u16x8 g0 = *(const u16x8*)(xlr + (size_t)e0 * 2048 + eoff);
        u16x8 g1 = *(const u16x8*)(xlr + (size_t)e1 * 2048 + eoff);
        float x0[8], x1[8];
#pragma unroll
        for (int v = 0; v < 8; ++v) { x0[v] = bf2f(g0[v]); x1[v] = bf2f(g1[v]); }
        float q0 = 0.f, q1 = 0.f;
#pragma unroll
        for (int v = 0; v < 8; ++v) {
            q0 += a[v] * lrelu(x0[v] + r[v]);
            q1 += a[v] * lrelu(x1[v] + r[v]);
        }
#pragma unroll
        for (int m = 1; m < 32; m <<= 1) {   // reduce within 32-lane half (one head)
            q0 += __shfl_xor(q0, m);
            q1 += __shfl_xor(q1, m);
        }
        q0 = fminf(fmaxf(q0, -60.f), 60.f);
        q1 = fminf(fmaxf(q1, -60.f), 60.f);
        float w0 = __expf(q0);
        float w1 = has1 ? __expf(q1) : 0.f;
        s += w0 + w1;
#pragma unroll
        for (int v = 0; v < 8; ++v) acc[v] += w0 * x0[v] + w1 * x1[v];
    }

    float inv = 1.0f / s;   // s identical across the 32-lane half
#pragma unroll
    for (int v = 0; v < 8; ++v) accLds[h][gl * 8 + v] = acc[v] * inv;
    __syncthreads();

    {   // head-mean + bias + lrelu + hi/lo split; thread t owns channels t, t+128
        int c0 = t, c1 = t + 128;
        float v0 = (accLds[0][c0] + accLds[1][c0] + accLds[2][c0] + accLds[3][c0]) * 0.25f + bias[c0];
        float v1 = (accLds[0][c1] + accLds[1][c1] + accLds[2][c1] + accLds[3][c1]) * 0.25f + bias[c1];
        v0 = lrelu(v0); v1 = lrelu(v1);
        unsigned short h0 = f2bf_rne(v0), h1v = f2bf_rne(v1);
        outH[(size_t)n * 256 + c0] = h0;
        outH[(size_t)n * 256 + c1] = h1v;
        outL[(size_t)n * 256 + c0] = f2bf_rne(v0 - bf2f(h0));
        outL[(size_t)n * 256 + c1] = f2bf_rne(v1 - bf2f(h1v));
    }
}

// ---------------- layer-2 fused aggregate: one wave per node ----------------
// Wave's 64 lanes cover the whole 1KB xl row (all 4 heads) in ONE contiguous
// load. Logit reduce = 4 shfl in 16-lane groups; head-mean via shfl 16/32.
// No LDS, no syncthreads. 4 nodes per 256-thread block.
__global__ __launch_bounds__(256) void agg2(const unsigned short* __restrict__ xlr,  // [N][1024]
                                            const float* __restrict__ att,           // [4][128]
                                            const int* __restrict__ offsets,
                                            const int* __restrict__ esrc,
                                            const float* __restrict__ bias,          // [128]
                                            float* __restrict__ out, int N) {
    const int lane = threadIdx.x & 63;
    const int n = blockIdx.x * 4 + (threadIdx.x >> 6);
    if (n >= N) return;
    const int h = lane >> 4, gl = lane & 15;
    const int eoff = lane * 8;   // element offset within xl row (0..511)

    float a[8], bs[8];
    {
        const float* pa = att + h * 128 + gl * 8;
        float4 a0 = *(const float4*)pa, a1 = *(const float4*)(pa + 4);
        a[0] = a0.x; a[1] = a0.y; a[2] = a0.z; a[3] = a0.w;
        a[4] = a1.x; a[5] = a1.y; a[6] = a1.z; a[7] = a1.w;
        const float* pb = bias + gl * 8;
        float4 b0 = *(const float4*)pb, b1v = *(const float4*)(pb + 4);
        bs[0] = b0.x; bs[1] = b0.y; bs[2] = b0.z; bs[3] = b0.w;
        bs[4] = b1v.x; bs[5] = b1v.y; bs[6] = b1v.z; bs[7] = b1v.w;
    }
    float r[8];
    {
        u16x8 u = *(const u16x8*)(xlr + (size_t)n * 1024 + 512 + eoff);
#pragma unroll
        for (int v = 0; v < 8; ++v) r[v] = bf2f(u[v]);
    }
    int o0 = offsets[n];
    int deg = offsets[n + 1] - o0;

    float acc[8];
#pragma unroll
    for (int v = 0; v < 8; ++v) acc[v] = 0.f;
    float s = 0.f;

    for (int j = 0; j < deg; j += 2) {
        int e0 = esrc[o0 + j];
        bool has1 = (j + 1) < deg;
        int e1 = esrc[o0 + (has1 ? j + 1 : j)];
        u16x8 g0 = *(const u16x8*)(xlr + (size_t)e0 * 1024 + eoff);
        u16x8 g1 = *(const u16x8*)(xlr + (size_t)e1 * 1024 + eoff);
        float x0[8], x1[8];
#pragma unroll
        for (int v = 0; v < 8; ++v) { x0[v] = bf2f(g0[v]); x1[v] = bf2f(g1[v]); }
        float q0 = 0.f, q1 = 0.f;
#pragma unroll
        for (int v = 0; v < 8; ++v) {
            q0 += a[v] * lrelu(x0[v] + r[v]);
            q1 += a[v] * lrelu(x1[v] + r[v]);
        }
#pragma unroll
        for (int m = 1; m < 16; m <<= 1) {   // reduce within 16-lane group (one head)
            q0 += __shfl_xor(q0, m);
            q1 += __shfl_xor(q1, m);
        }
        q0 = fminf(fmaxf(q0, -60.f), 60.f);
        q1 = fminf(fmaxf(q1, -60.f), 60.f);
        float w0 = __expf(q0);
        float w1 = has1 ? __expf(q1) : 0.f;
        s += w0 + w1;
#pragma unroll
        for (int v = 0; v < 8; ++v) acc[v] += w0 * x0[v] + w1 * x1[v];
    }

    float inv = 1.0f / s;
#pragma unroll
    for (int v = 0; v < 8; ++v) acc[v] *= inv;
    // head-mean: normalize first, then cross-group sum
#pragma unroll
    for (int v = 0; v < 8; ++v) {
        acc[v] += __shfl_xor(acc[v], 16);
        acc[v] += __shfl_xor(acc[v], 32);
    }
    if (h == 0) {
        float o[8];
#pragma unroll
        for (int v = 0; v < 8; ++v) o[v] = tanhf(acc[v] * 0.25f + bs[v]);
        float* po = out + (size_t)n * 128 + gl * 8;
        *(float4*)po = make_float4(o[0], o[1], o[2], o[3]);
        *(float4*)(po + 4) = make_float4(o[4], o[5], o[6], o[7]);
    }
}

// ---------------- launch ----------------

extern "C" void kernel_launch(void* const* d_in, const int* in_sizes, int n_in,
                              void* d_out, int out_size, void* d_ws, size_t ws_size,
                              hipStream_t stream) {
    const float* x    = (const float*)d_in[0];
    const int*   ei   = (const int*)d_in[1];
    const float* Wl1  = (const float*)d_in[2];
    const float* Wr1  = (const float*)d_in[3];
    const float* att1 = (const float*)d_in[4];
    const float* b1   = (const float*)d_in[5];
    const float* Wl2  = (const float*)d_in[6];
    const float* Wr2  = (const float*)d_in[7];
    const float* att2 = (const float*)d_in[8];
    const float* b2   = (const float*)d_in[9];
    float* out = (float*)d_out;

    const int IN = 512, HID = 256, OUT = 128, H = 4;
    int N  = in_sizes[0] / IN;
    int E  = in_sizes[1] / 2;
    int ET = E + N;
    int M2 = ((N + 127) / 128) * 128;   // 10112

    char* w = (char*)d_ws;
    auto carve = [&](size_t bytes) {
        char* p = w;
        w += (bytes + 255) & ~(size_t)255;
        return (void*)p;
    };
    unsigned short* x_hi = (unsigned short*)carve((size_t)M2 * IN * 2);
    unsigned short* xlr1 = (unsigned short*)carve((size_t)N * 2 * H * HID * 2);
    unsigned short* BT1 = (unsigned short*)carve((size_t)(2 * H * HID) * IN * 2);
    int* src     = (int*)carve((size_t)ET * 4);
    int* dst     = (int*)carve((size_t)ET * 4);
    int* counts  = (int*)carve((size_t)N * 4);
    int* cursor  = (int*)carve((size_t)N * 4);
    int* offsets = (int*)carve((size_t)(N + 1) * 4);
    int* esrc    = (int*)carve((size_t)ET * 4);
    unsigned short* h1_h = x_hi;
    unsigned short* h1_l = x_hi + (size_t)M2 * HID;
    unsigned short* xlr2 = xlr1;
    unsigned short* BT2  = BT1;

    // ---- CSR build ----
    hipMemsetAsync(counts, 0, (size_t)((char*)offsets - (char*)counts), stream);
    build_edges<<<(ET + 255) / 256, 256, 0, stream>>>(ei, E, N, src, dst, counts);
    scan_offsets<<<1, 1024, 0, stream>>>(counts, offsets, N);
    fill_eids<<<(ET + 255) / 256, 256, 0, stream>>>(src, dst, offsets, cursor, esrc, ET);

    // ---- prep layer 1 ----
    {
        int total4 = M2 * IN / 4;
        conv_hi<<<(total4 + 255) / 256, 256, 0, stream>>>(x, x_hi, N, 9, total4);
        thi<<<dim3((H * HID) / 32, IN / 32), dim3(32, 8), 0, stream>>>(Wl1, BT1, IN, H * HID);
        thi<<<dim3((H * HID) / 32, IN / 32), dim3(32, 8), 0, stream>>>(Wr1, BT1 + (size_t)(H * HID) * IN, IN, H * HID);
    }
    // ---- layer 1 GEMM (combined Wl|Wr, pure bf16, bf16 out) ----
    {
        dim3 g((2 * H * HID) / 128, M2 / 128);
        gemm_mfma<1, true><<<g, 256, 0, stream>>>(x_hi, nullptr, BT1, nullptr, xlr1, N, 2 * H * HID, IN);
    }
    // ---- layer 1 aggregate: block per node, contiguous 1KB gathers ----
    agg1<<<M2, 128, 0, stream>>>(xlr1, att1, offsets, esrc, b1, h1_h, h1_l, N);
    // ---- prep layer 2 ----
    thi<<<dim3((H * OUT) / 32, HID / 32), dim3(32, 8), 0, stream>>>(Wl2, BT2, HID, H * OUT);
    thi<<<dim3((H * OUT) / 32, HID / 32), dim3(32, 8), 0, stream>>>(Wr2, BT2 + (size_t)(H * OUT) * HID, HID, H * OUT);
    // ---- layer 2 GEMM (combined, 2-term, bf16 out) ----
    {
        dim3 g((2 * H * OUT) / 128, M2 / 128);
        gemm_mfma<2, true><<<g, 256, 0, stream>>>(h1_h, h1_l, BT2, nullptr, xlr2, N, 2 * H * OUT, HID);
    }
    // ---- layer 2 aggregate: wave per node, one contiguous 1KB gather ----
    agg2<<<(N + 3) / 4, 256, 0, stream>>>(xlr2, att2, offsets, esrc, b2, out, N);
}

// Round 11
// 186.302 us; speedup vs baseline: 1.0015x; 1.0015x over previous
//
#include <hip/hip_runtime.h>
#include <hip/hip_bf16.h>
#include <math.h>

#define DEVINL __device__ __forceinline__

typedef __attribute__((ext_vector_type(8))) short bf16x8;
typedef __attribute__((ext_vector_type(8))) unsigned short u16x8;
typedef __attribute__((ext_vector_type(4))) float f32x4;

DEVINL float lrelu(float x) { return x > 0.f ? x : 0.2f * x; }

DEVINL unsigned short f2bf_rne(float f) {
    unsigned u = __float_as_uint(f);
    unsigned r = u + 0x7fff + ((u >> 16) & 1);
    return (unsigned short)(r >> 16);
}
DEVINL float bf2f(unsigned short h) { return __uint_as_float(((unsigned)h) << 16); }

DEVINL void gload_lds16(const void* g, void* l) {
    __builtin_amdgcn_global_load_lds(
        (const __attribute__((address_space(1))) void*)g,
        (__attribute__((address_space(3))) void*)l, 16, 0, 0);
}

// ---------------- CSR build ----------------

__global__ void build_edges(const int* __restrict__ ei, int E, int N,
                            int* __restrict__ src, int* __restrict__ dst,
                            int* __restrict__ counts) {
    int e = blockIdx.x * 256 + threadIdx.x;
    int ET = E + N;
    if (e >= ET) return;
    int s, d;
    if (e < E) { s = ei[e]; d = ei[E + e]; }
    else       { s = d = e - E; }
    s = min(max(s, 0), N - 1);
    d = min(max(d, 0), N - 1);
    src[e] = s;
    dst[e] = d;
    atomicAdd(&counts[d], 1);
}

__global__ void scan_offsets(const int* __restrict__ counts, int* __restrict__ offsets, int N) {
    const int T = 1024;
    __shared__ int sums[T];
    int t = threadIdx.x;
    int chunk = (N + T - 1) / T;
    int base = t * chunk;
    int local[16];
    int s = 0;
    for (int i = 0; i < chunk; ++i) {
        int v = (base + i < N) ? counts[base + i] : 0;
        local[i] = s;
        s += v;
    }
    sums[t] = s;
    __syncthreads();
    for (int d = 1; d < T; d <<= 1) {
        int v = (t >= d) ? sums[t - d] : 0;
        __syncthreads();
        sums[t] += v;
        __syncthreads();
    }
    int excl = (t == 0) ? 0 : sums[t - 1];
    for (int i = 0; i < chunk; ++i)
        if (base + i < N) offsets[base + i] = excl + local[i];
    if (t == T - 1) offsets[N] = excl + s;
}

__global__ void fill_eids(const int* __restrict__ src, const int* __restrict__ dst,
                          const int* __restrict__ offsets,
                          int* __restrict__ cursor, int* __restrict__ esrc, int ET) {
    int e = blockIdx.x * 256 + threadIdx.x;
    if (e >= ET) return;
    int d = dst[e];
    int pos = offsets[d] + atomicAdd(&cursor[d], 1);
    esrc[pos] = src[e];
}

// ---------------- f32 -> hi bf16 (RNE), zero-padded rows >= M ----------------
__global__ void conv_hi(const float* __restrict__ x, unsigned short* __restrict__ hi,
                        int M, int log2K, int total4) {
    int i = blockIdx.x * 256 + threadIdx.x;
    if (i >= total4) return;
    int e = i * 4;
    int row = e >> log2K;
    ushort4 vh = make_ushort4(0, 0, 0, 0);
    if (row < M) {
        float4 v = *(const float4*)&x[e];
        vh = make_ushort4(f2bf_rne(v.x), f2bf_rne(v.y), f2bf_rne(v.z), f2bf_rne(v.w));
    }
    *(ushort4*)&hi[e] = vh;
}

// ---------------- W[K][Nout] f32 -> BT[Nout][K] hi bf16 ----------------
__global__ void thi(const float* __restrict__ W, unsigned short* __restrict__ BTh,
                    int K, int Nout) {
    __shared__ float tile[32][33];
    int n0 = blockIdx.x * 32, k0 = blockIdx.y * 32;
    int tx = threadIdx.x, ty = threadIdx.y;
#pragma unroll
    for (int i = 0; i < 4; ++i)
        tile[ty + 8 * i][tx] = W[(size_t)(k0 + ty + 8 * i) * Nout + n0 + tx];
    __syncthreads();
#pragma unroll
    for (int i = 0; i < 4; ++i) {
        int r = ty + 8 * i;
        BTh[(size_t)(n0 + r) * K + k0 + tx] = f2bf_rne(tile[tx][r]);
    }
}

// ---------------- bf16 MFMA GEMM: C[M][Nout] = A[M2][K] @ BT[Nout][K]^T ----------------
// 128x128 tile, BK=64, 4 waves (2x2), 16x16x32 bf16 MFMA, T1 bijective XCD swizzle.
template <int TERMS, bool OUTBF16>
__global__ __launch_bounds__(256) void gemm_mfma(
    const unsigned short* __restrict__ Ah, const unsigned short* __restrict__ Al,
    const unsigned short* __restrict__ Bh,
    float* __restrict__ Cf, unsigned short* __restrict__ Cb,
    int M, int Nout, int K) {
    constexpr int BOFF = (TERMS == 2) ? 32768 : 16384;
    __shared__ __align__(16) char lds[BOFF + 16384];
    const int t = threadIdx.x;
    const int L = t & 63, w = t >> 6;
    const int wm = w & 1, wn = w >> 1;
    const int nwg = gridDim.x * gridDim.y;
    int orig = blockIdx.y * gridDim.x + blockIdx.x;
    int q = nwg >> 3, rr = nwg & 7;
    int xcd = orig & 7, pos = orig >> 3;
    int wg = (xcd < rr ? xcd * (q + 1) : rr * (q + 1) + (xcd - rr) * q) + pos;
    const int bm = (wg / gridDim.x) * 128, bn = (wg % gridDim.x) * 128;
    const size_t strideA = (size_t)K * 2;

    const f32x4 vzero = {0.f, 0.f, 0.f, 0.f};
    f32x4 acc[4][4];
#pragma unroll
    for (int i = 0; i < 4; ++i)
#pragma unroll
        for (int j = 0; j < 4; ++j) acc[i][j] = vzero;

    for (int k0 = 0; k0 < K; k0 += 64) {
#pragma unroll
        for (int i = 0; i < 4; ++i) {
            int slot = i * 256 + t;
            int offs = slot * 16;
            int r = offs >> 7;
            int cb = (offs & 127) ^ ((r & 7) << 4);
            size_t gofs = (size_t)r * strideA + (size_t)k0 * 2 + cb;
            gload_lds16((const char*)Ah + (size_t)bm * strideA + gofs, lds + offs);
            if constexpr (TERMS == 2)
                gload_lds16((const char*)Al + (size_t)bm * strideA + gofs, lds + 16384 + offs);
            gload_lds16((const char*)Bh + (size_t)bn * strideA + gofs, lds + BOFF + offs);
        }
        __syncthreads();
#pragma unroll
        for (int kf = 0; kf < 2; ++kf) {
            const int kb = kf * 64 + ((L >> 4) * 16);
            bf16x8 ah[4], al[4], bh[4];
#pragma unroll
            for (int mi = 0; mi < 4; ++mi) {
                int r = wm * 64 + mi * 16 + (L & 15);
                int off = r * 128 + (kb ^ ((r & 7) << 4));
                ah[mi] = *(const bf16x8*)(lds + off);
                if constexpr (TERMS == 2) al[mi] = *(const bf16x8*)(lds + 16384 + off);
            }
#pragma unroll
            for (int ni = 0; ni < 4; ++ni) {
                int r = wn * 64 + ni * 16 + (L & 15);
                int off = r * 128 + (kb ^ ((r & 7) << 4));
                bh[ni] = *(const bf16x8*)(lds + BOFF + off);
            }
#pragma unroll
            for (int mi = 0; mi < 4; ++mi)
#pragma unroll
                for (int ni = 0; ni < 4; ++ni) {
                    acc[mi][ni] = __builtin_amdgcn_mfma_f32_16x16x32_bf16(ah[mi], bh[ni], acc[mi][ni], 0, 0, 0);
                    if constexpr (TERMS == 2)
                        acc[mi][ni] = __builtin_amdgcn_mfma_f32_16x16x32_bf16(al[mi], bh[ni], acc[mi][ni], 0, 0, 0);
                }
        }
        __syncthreads();
    }
    const int colBase = bn + wn * 64 + (L & 15);
#pragma unroll
    for (int mi = 0; mi < 4; ++mi) {
        int row0 = bm + wm * 64 + mi * 16 + (L >> 4) * 4;
#pragma unroll
        for (int j = 0; j < 4; ++j) {
            int row = row0 + j;
            if (row < M) {
#pragma unroll
                for (int ni = 0; ni < 4; ++ni) {
                    if constexpr (OUTBF16)
                        Cb[(size_t)row * Nout + colBase + ni * 16] = f2bf_rne(acc[mi][ni][j]);
                    else
                        Cf[(size_t)row * Nout + colBase + ni * 16] = acc[mi][ni][j];
                }
            }
        }
    }
}

// ---------------- layer-1 fused aggregate: block(128) per node ----------------
// Wave w (of 2) covers heads 2w,2w+1: its 64 lanes read ONE contiguous 1KB
// (lane-stride 16B, each cache line requested exactly once — round-4 access
// shape). Logit reduce = 5 shfl within 32-lane half; head-merge via 4KB LDS;
// fused bias + lrelu + hi/lo bf16 split write. Rows >= N zero-padded.
__global__ __launch_bounds__(128) void agg1(const unsigned short* __restrict__ xlr,  // [M2][2048]
                                            const float* __restrict__ att,           // [4][256]
                                            const int* __restrict__ offsets,
                                            const int* __restrict__ esrc,
                                            const float* __restrict__ bias,          // [256]
                                            unsigned short* __restrict__ outH,
                                            unsigned short* __restrict__ outL,
                                            int N) {
    __shared__ float accLds[4][256];
    const int t = threadIdx.x;
    const int wv = t >> 6, lane = t & 63;
    const int n = blockIdx.x;

    if (n >= N) {   // zero-pad rows for downstream MFMA GEMM
        int c = t * 2;
        *(ushort2*)&outH[(size_t)n * 256 + c] = make_ushort2(0, 0);
        *(ushort2*)&outL[(size_t)n * 256 + c] = make_ushort2(0, 0);
        return;
    }

    const int eoff = 512 * wv + lane * 8;   // element offset within xl row (0..1023)
    const int h = eoff >> 8;                // head 0..3
    const int gl = lane & 31;               // 8-channel group within head

    float a[8];
    {
        const float* pa = att + h * 256 + gl * 8;
        float4 a0 = *(const float4*)pa, a1 = *(const float4*)(pa + 4);
        a[0] = a0.x; a[1] = a0.y; a[2] = a0.z; a[3] = a0.w;
        a[4] = a1.x; a[5] = a1.y; a[6] = a1.z; a[7] = a1.w;
    }
    float r[8];
    {
        u16x8 u = *(const u16x8*)(xlr + (size_t)n * 2048 + 1024 + eoff);
#pragma unroll
        for (int v = 0; v < 8; ++v) r[v] = bf2f(u[v]);
    }
    int o0 = offsets[n];
    int deg = offsets[n + 1] - o0;

    float acc[8];
#pragma unroll
    for (int v = 0; v < 8; ++v) acc[v] = 0.f;
    float s = 0.f;

    for (int j = 0; j < deg; j += 2) {
        int e0 = esrc[o0 + j];
        bool has1 = (j + 1) < deg;
        int e1 = esrc[o0 + (has1 ? j + 1 : j)];
        u16x8 g0 = *(const u16x8*)(xlr + (size_t)e0 * 2048 + eoff);
        u16x8 g1 = *(const u16x8*)(xlr + (size_t)e1 * 2048 + eoff);
        float x0[8], x1[8];
#pragma unroll
        for (int v = 0; v < 8; ++v) { x0[v] = bf2f(g0[v]); x1[v] = bf2f(g1[v]); }
        float q0 = 0.f, q1 = 0.f;
#pragma unroll
        for (int v = 0; v < 8; ++v) {
            q0 += a[v] * lrelu(x0[v] + r[v]);
            q1 += a[v] * lrelu(x1[v] + r[v]);
        }
#pragma unroll
        for (int m = 1; m < 32; m <<= 1) {   // reduce within 32-lane half (one head)
            q0 += __shfl_xor(q0, m);
            q1 += __shfl_xor(q1, m);
        }
        q0 = fminf(fmaxf(q0, -60.f), 60.f);
        q1 = fminf(fmaxf(q1, -60.f), 60.f);
        float w0 = __expf(q0);
        float w1 = has1 ? __expf(q1) : 0.f;
        s += w0 + w1;
#pragma unroll
        for (int v = 0; v < 8; ++v) acc[v] += w0 * x0[v] + w1 * x1[v];
    }

    float inv = 1.0f / s;   // s identical across the 32-lane half
#pragma unroll
    for (int v = 0; v < 8; ++v) accLds[h][gl * 8 + v] = acc[v] * inv;
    __syncthreads();

    {   // head-mean + bias + lrelu + hi/lo split; thread t owns channels t, t+128
        int c0 = t, c1 = t + 128;
        float v0 = (accLds[0][c0] + accLds[1][c0] + accLds[2][c0] + accLds[3][c0]) * 0.25f + bias[c0];
        float v1 = (accLds[0][c1] + accLds[1][c1] + accLds[2][c1] + accLds[3][c1]) * 0.25f + bias[c1];
        v0 = lrelu(v0); v1 = lrelu(v1);
        unsigned short h0 = f2bf_rne(v0), h1v = f2bf_rne(v1);
        outH[(size_t)n * 256 + c0] = h0;
        outH[(size_t)n * 256 + c1] = h1v;
        outL[(size_t)n * 256 + c0] = f2bf_rne(v0 - bf2f(h0));
        outL[(size_t)n * 256 + c1] = f2bf_rne(v1 - bf2f(h1v));
    }
}

// ---------------- layer-2 fused aggregate: one wave per node ----------------
// Wave's 64 lanes cover the whole 1KB xl row (all 4 heads) in ONE contiguous
// load. Logit reduce = 4 shfl in 16-lane groups; head-mean via shfl 16/32.
// No LDS, no syncthreads. 4 nodes per 256-thread block.
__global__ __launch_bounds__(256) void agg2(const unsigned short* __restrict__ xlr,  // [N][1024]
                                            const float* __restrict__ att,           // [4][128]
                                            const int* __restrict__ offsets,
                                            const int* __restrict__ esrc,
                                            const float* __restrict__ bias,          // [128]
                                            float* __restrict__ out, int N) {
    const int lane = threadIdx.x & 63;
    const int n = blockIdx.x * 4 + (threadIdx.x >> 6);
    if (n >= N) return;
    const int h = lane >> 4, gl = lane & 15;
    const int eoff = lane * 8;   // element offset within xl row (0..511)

    float a[8], bs[8];
    {
        const float* pa = att + h * 128 + gl * 8;
        float4 a0 = *(const float4*)pa, a1 = *(const float4*)(pa + 4);
        a[0] = a0.x; a[1] = a0.y; a[2] = a0.z; a[3] = a0.w;
        a[4] = a1.x; a[5] = a1.y; a[6] = a1.z; a[7] = a1.w;
        const float* pb = bias + gl * 8;
        float4 b0 = *(const float4*)pb, b1v = *(const float4*)(pb + 4);
        bs[0] = b0.x; bs[1] = b0.y; bs[2] = b0.z; bs[3] = b0.w;
        bs[4] = b1v.x; bs[5] = b1v.y; bs[6] = b1v.z; bs[7] = b1v.w;
    }
    float r[8];
    {
        u16x8 u = *(const u16x8*)(xlr + (size_t)n * 1024 + 512 + eoff);
#pragma unroll
        for (int v = 0; v < 8; ++v) r[v] = bf2f(u[v]);
    }
    int o0 = offsets[n];
    int deg = offsets[n + 1] - o0;

    float acc[8];
#pragma unroll
    for (int v = 0; v < 8; ++v) acc[v] = 0.f;
    float s = 0.f;

    for (int j = 0; j < deg; j += 2) {
        int e0 = esrc[o0 + j];
        bool has1 = (j + 1) < deg;
        int e1 = esrc[o0 + (has1 ? j + 1 : j)];
        u16x8 g0 = *(const u16x8*)(xlr + (size_t)e0 * 1024 + eoff);
        u16x8 g1 = *(const u16x8*)(xlr + (size_t)e1 * 1024 + eoff);
        float x0[8], x1[8];
#pragma unroll
        for (int v = 0; v < 8; ++v) { x0[v] = bf2f(g0[v]); x1[v] = bf2f(g1[v]); }
        float q0 = 0.f, q1 = 0.f;
#pragma unroll
        for (int v = 0; v < 8; ++v) {
            q0 += a[v] * lrelu(x0[v] + r[v]);
            q1 += a[v] * lrelu(x1[v] + r[v]);
        }
#pragma unroll
        for (int m = 1; m < 16; m <<= 1) {   // reduce within 16-lane group (one head)
            q0 += __shfl_xor(q0, m);
            q1 += __shfl_xor(q1, m);
        }
        q0 = fminf(fmaxf(q0, -60.f), 60.f);
        q1 = fminf(fmaxf(q1, -60.f), 60.f);
        float w0 = __expf(q0);
        float w1 = has1 ? __expf(q1) : 0.f;
        s += w0 + w1;
#pragma unroll
        for (int v = 0; v < 8; ++v) acc[v] += w0 * x0[v] + w1 * x1[v];
    }

    float inv = 1.0f / s;
#pragma unroll
    for (int v = 0; v < 8; ++v) acc[v] *= inv;
    // head-mean: normalize first, then cross-group sum
#pragma unroll
    for (int v = 0; v < 8; ++v) {
        acc[v] += __shfl_xor(acc[v], 16);
        acc[v] += __shfl_xor(acc[v], 32);
    }
    if (h == 0) {
        float o[8];
#pragma unroll
        for (int v = 0; v < 8; ++v) o[v] = tanhf(acc[v] * 0.25f + bs[v]);
        float* po = out + (size_t)n * 128 + gl * 8;
        *(float4*)po = make_float4(o[0], o[1], o[2], o[3]);
        *(float4*)(po + 4) = make_float4(o[4], o[5], o[6], o[7]);
    }
}

// ---------------- launch ----------------

extern "C" void kernel_launch(void* const* d_in, const int* in_sizes, int n_in,
                              void* d_out, int out_size, void* d_ws, size_t ws_size,
                              hipStream_t stream) {
    const float* x    = (const float*)d_in[0];
    const int*   ei   = (const int*)d_in[1];
    const float* Wl1  = (const float*)d_in[2];
    const float* Wr1  = (const float*)d_in[3];
    const float* att1 = (const float*)d_in[4];
    const float* b1   = (const float*)d_in[5];
    const float* Wl2  = (const float*)d_in[6];
    const float* Wr2  = (const float*)d_in[7];
    const float* att2 = (const float*)d_in[8];
    const float* b2   = (const float*)d_in[9];
    float* out = (float*)d_out;

    const int IN = 512, HID = 256, OUT = 128, H = 4;
    int N  = in_sizes[0] / IN;
    int E  = in_sizes[1] / 2;
    int ET = E + N;
    int M2 = ((N + 127) / 128) * 128;   // 10112

    char* w = (char*)d_ws;
    auto carve = [&](size_t bytes) {
        char* p = w;
        w += (bytes + 255) & ~(size_t)255;
        return (void*)p;
    };
    unsigned short* x_hi = (unsigned short*)carve((size_t)M2 * IN * 2);
    unsigned short* xlr1 = (unsigned short*)carve((size_t)N * 2 * H * HID * 2);
    unsigned short* BT1 = (unsigned short*)carve((size_t)(2 * H * HID) * IN * 2);
    int* src     = (int*)carve((size_t)ET * 4);
    int* dst     = (int*)carve((size_t)ET * 4);
    int* counts  = (int*)carve((size_t)N * 4);
    int* cursor  = (int*)carve((size_t)N * 4);
    int* offsets = (int*)carve((size_t)(N + 1) * 4);
    int* esrc    = (int*)carve((size_t)ET * 4);
    unsigned short* h1_h = x_hi;
    unsigned short* h1_l = x_hi + (size_t)M2 * HID;
    unsigned short* xlr2 = xlr1;
    unsigned short* BT2  = BT1;

    // ---- CSR build ----
    hipMemsetAsync(counts, 0, (size_t)((char*)offsets - (char*)counts), stream);
    build_edges<<<(ET + 255) / 256, 256, 0, stream>>>(ei, E, N, src, dst, counts);
    scan_offsets<<<1, 1024, 0, stream>>>(counts, offsets, N);
    fill_eids<<<(ET + 255) / 256, 256, 0, stream>>>(src, dst, offsets, cursor, esrc, ET);

    // ---- prep layer 1 ----
    {
        int total4 = M2 * IN / 4;
        conv_hi<<<(total4 + 255) / 256, 256, 0, stream>>>(x, x_hi, N, 9, total4);
        thi<<<dim3((H * HID) / 32, IN / 32), dim3(32, 8), 0, stream>>>(Wl1, BT1, IN, H * HID);
        thi<<<dim3((H * HID) / 32, IN / 32), dim3(32, 8), 0, stream>>>(Wr1, BT1 + (size_t)(H * HID) * IN, IN, H * HID);
    }
    // ---- layer 1 GEMM (combined Wl|Wr, pure bf16, bf16 out) ----
    {
        dim3 g((2 * H * HID) / 128, M2 / 128);
        gemm_mfma<1, true><<<g, 256, 0, stream>>>(x_hi, nullptr, BT1, nullptr, xlr1, N, 2 * H * HID, IN);
    }
    // ---- layer 1 aggregate: block per node, contiguous 1KB gathers ----
    agg1<<<M2, 128, 0, stream>>>(xlr1, att1, offsets, esrc, b1, h1_h, h1_l, N);
    // ---- prep layer 2 ----
    thi<<<dim3((H * OUT) / 32, HID / 32), dim3(32, 8), 0, stream>>>(Wl2, BT2, HID, H * OUT);
    thi<<<dim3((H * OUT) / 32, HID / 32), dim3(32, 8), 0, stream>>>(Wr2, BT2 + (size_t)(H * OUT) * HID, HID, H * OUT);
    // ---- layer 2 GEMM (combined, 2-term, bf16 out) ----
    {
        dim3 g((2 * H * OUT) / 128, M2 / 128);
        gemm_mfma<2, true><<<g, 256, 0, stream>>>(h1_h, h1_l, BT2, nullptr, xlr2, N, 2 * H * OUT, HID);
    }
    // ---- layer 2 aggregate: wave per node, one contiguous 1KB gather ----
    agg2<<<(N + 3) / 4, 256, 0, stream>>>(xlr2, att2, offsets, esrc, b2, out, N);
}

// Round 12
// 185.787 us; speedup vs baseline: 1.0043x; 1.0028x over previous
//
#include <hip/hip_runtime.h>
#include <hip/hip_bf16.h>
#include <math.h>

#define DEVINL __device__ __forceinline__

typedef __attribute__((ext_vector_type(8))) short bf16x8;
typedef __attribute__((ext_vector_type(8))) unsigned short u16x8;
typedef __attribute__((ext_vector_type(4))) float f32x4;

DEVINL float lrelu(float x) { return x > 0.f ? x : 0.2f * x; }

DEVINL unsigned short f2bf_rne(float f) {
    unsigned u = __float_as_uint(f);
    unsigned r = u + 0x7fff + ((u >> 16) & 1);
    return (unsigned short)(r >> 16);
}
DEVINL float bf2f(unsigned short h) { return __uint_as_float(((unsigned)h) << 16); }

DEVINL void gload_lds16(const void* g, void* l) {
    __builtin_amdgcn_global_load_lds(
        (const __attribute__((address_space(1))) void*)g,
        (__attribute__((address_space(3))) void*)l, 16, 0, 0);
}

// ---------------- CSR build ----------------

__global__ void build_edges(const int* __restrict__ ei, int E, int N,
                            int* __restrict__ src, int* __restrict__ dst,
                            int* __restrict__ counts) {
    int e = blockIdx.x * 256 + threadIdx.x;
    int ET = E + N;
    if (e >= ET) return;
    int s, d;
    if (e < E) { s = ei[e]; d = ei[E + e]; }
    else       { s = d = e - E; }
    s = min(max(s, 0), N - 1);
    d = min(max(d, 0), N - 1);
    src[e] = s;
    dst[e] = d;
    atomicAdd(&counts[d], 1);
}

__global__ void scan_offsets(const int* __restrict__ counts, int* __restrict__ offsets, int N) {
    const int T = 1024;
    __shared__ int sums[T];
    int t = threadIdx.x;
    int chunk = (N + T - 1) / T;
    int base = t * chunk;
    int local[16];
    int s = 0;
    for (int i = 0; i < chunk; ++i) {
        int v = (base + i < N) ? counts[base + i] : 0;
        local[i] = s;
        s += v;
    }
    sums[t] = s;
    __syncthreads();
    for (int d = 1; d < T; d <<= 1) {
        int v = (t >= d) ? sums[t - d] : 0;
        __syncthreads();
        sums[t] += v;
        __syncthreads();
    }
    int excl = (t == 0) ? 0 : sums[t - 1];
    for (int i = 0; i < chunk; ++i)
        if (base + i < N) offsets[base + i] = excl + local[i];
    if (t == T - 1) offsets[N] = excl + s;
}

__global__ void fill_eids(const int* __restrict__ src, const int* __restrict__ dst,
                          const int* __restrict__ offsets,
                          int* __restrict__ cursor, int* __restrict__ esrc, int ET) {
    int e = blockIdx.x * 256 + threadIdx.x;
    if (e >= ET) return;
    int d = dst[e];
    int pos = offsets[d] + atomicAdd(&cursor[d], 1);
    esrc[pos] = src[e];
}

// ---------------- f32 -> hi bf16 (RNE), zero-padded rows >= M ----------------
__global__ void conv_hi(const float* __restrict__ x, unsigned short* __restrict__ hi,
                        int M, int log2K, int total4) {
    int i = blockIdx.x * 256 + threadIdx.x;
    if (i >= total4) return;
    int e = i * 4;
    int row = e >> log2K;
    ushort4 vh = make_ushort4(0, 0, 0, 0);
    if (row < M) {
        float4 v = *(const float4*)&x[e];
        vh = make_ushort4(f2bf_rne(v.x), f2bf_rne(v.y), f2bf_rne(v.z), f2bf_rne(v.w));
    }
    *(ushort4*)&hi[e] = vh;
}

// ---------------- W[K][Nout] f32 -> BT[Nout][K] hi bf16 ----------------
__global__ void thi(const float* __restrict__ W, unsigned short* __restrict__ BTh,
                    int K, int Nout) {
    __shared__ float tile[32][33];
    int n0 = blockIdx.x * 32, k0 = blockIdx.y * 32;
    int tx = threadIdx.x, ty = threadIdx.y;
#pragma unroll
    for (int i = 0; i < 4; ++i)
        tile[ty + 8 * i][tx] = W[(size_t)(k0 + ty + 8 * i) * Nout + n0 + tx];
    __syncthreads();
#pragma unroll
    for (int i = 0; i < 4; ++i) {
        int r = ty + 8 * i;
        BTh[(size_t)(n0 + r) * K + k0 + tx] = f2bf_rne(tile[tx][r]);
    }
}

// ---------------- bf16 MFMA GEMM: C[M][Nout] = A[M2][K] @ BT[Nout][K]^T ----------------
// 128x128 tile, BK=64, 4 waves (2x2), 16x16x32 bf16 MFMA, T1 bijective XCD swizzle.
template <int TERMS, bool OUTBF16>
__global__ __launch_bounds__(256) void gemm_mfma(
    const unsigned short* __restrict__ Ah, const unsigned short* __restrict__ Al,
    const unsigned short* __restrict__ Bh,
    float* __restrict__ Cf, unsigned short* __restrict__ Cb,
    int M, int Nout, int K) {
    constexpr int BOFF = (TERMS == 2) ? 32768 : 16384;
    __shared__ __align__(16) char lds[BOFF + 16384];
    const int t = threadIdx.x;
    const int L = t & 63, w = t >> 6;
    const int wm = w & 1, wn = w >> 1;
    const int nwg = gridDim.x * gridDim.y;
    int orig = blockIdx.y * gridDim.x + blockIdx.x;
    int q = nwg >> 3, rr = nwg & 7;
    int xcd = orig & 7, pos = orig >> 3;
    int wg = (xcd < rr ? xcd * (q + 1) : rr * (q + 1) + (xcd - rr) * q) + pos;
    const int bm = (wg / gridDim.x) * 128, bn = (wg % gridDim.x) * 128;
    const size_t strideA = (size_t)K * 2;

    const f32x4 vzero = {0.f, 0.f, 0.f, 0.f};
    f32x4 acc[4][4];
#pragma unroll
    for (int i = 0; i < 4; ++i)
#pragma unroll
        for (int j = 0; j < 4; ++j) acc[i][j] = vzero;

    for (int k0 = 0; k0 < K; k0 += 64) {
#pragma unroll
        for (int i = 0; i < 4; ++i) {
            int slot = i * 256 + t;
            int offs = slot * 16;
            int r = offs >> 7;
            int cb = (offs & 127) ^ ((r & 7) << 4);
            size_t gofs = (size_t)r * strideA + (size_t)k0 * 2 + cb;
            gload_lds16((const char*)Ah + (size_t)bm * strideA + gofs, lds + offs);
            if constexpr (TERMS == 2)
                gload_lds16((const char*)Al + (size_t)bm * strideA + gofs, lds + 16384 + offs);
            gload_lds16((const char*)Bh + (size_t)bn * strideA + gofs, lds + BOFF + offs);
        }
        __syncthreads();
#pragma unroll
        for (int kf = 0; kf < 2; ++kf) {
            const int kb = kf * 64 + ((L >> 4) * 16);
            bf16x8 ah[4], al[4], bh[4];
#pragma unroll
            for (int mi = 0; mi < 4; ++mi) {
                int r = wm * 64 + mi * 16 + (L & 15);
                int off = r * 128 + (kb ^ ((r & 7) << 4));
                ah[mi] = *(const bf16x8*)(lds + off);
                if constexpr (TERMS == 2) al[mi] = *(const bf16x8*)(lds + 16384 + off);
            }
#pragma unroll
            for (int ni = 0; ni < 4; ++ni) {
                int r = wn * 64 + ni * 16 + (L & 15);
                int off = r * 128 + (kb ^ ((r & 7) << 4));
                bh[ni] = *(const bf16x8*)(lds + BOFF + off);
            }
#pragma unroll
            for (int mi = 0; mi < 4; ++mi)
#pragma unroll
                for (int ni = 0; ni < 4; ++ni) {
                    acc[mi][ni] = __builtin_amdgcn_mfma_f32_16x16x32_bf16(ah[mi], bh[ni], acc[mi][ni], 0, 0, 0);
                    if constexpr (TERMS == 2)
                        acc[mi][ni] = __builtin_amdgcn_mfma_f32_16x16x32_bf16(al[mi], bh[ni], acc[mi][ni], 0, 0, 0);
                }
        }
        __syncthreads();
    }
    const int colBase = bn + wn * 64 + (L & 15);
#pragma unroll
    for (int mi = 0; mi < 4; ++mi) {
        int row0 = bm + wm * 64 + mi * 16 + (L >> 4) * 4;
#pragma unroll
        for (int j = 0; j < 4; ++j) {
            int row = row0 + j;
            if (row < M) {
#pragma unroll
                for (int ni = 0; ni < 4; ++ni) {
                    if constexpr (OUTBF16)
                        Cb[(size_t)row * Nout + colBase + ni * 16] = f2bf_rne(acc[mi][ni][j]);
                    else
                        Cf[(size_t)row * Nout + colBase + ni * 16] = acc[mi][ni][j];
                }
            }
        }
    }
}

// ---------------- layer-1 fused aggregate: block(128) per node ----------------
// Wave w (of 2) covers heads 2w,2w+1: its 64 lanes read ONE contiguous 1KB
// (lane-stride 16B, each cache line requested exactly once — round-4 access
// shape). Logit reduce = 5 shfl within 32-lane half; head-merge via 4KB LDS;
// fused bias + lrelu + hi/lo bf16 split write. Rows >= N zero-padded.
__global__ __launch_bounds__(128) void agg1(const unsigned short* __restrict__ xlr,  // [M2][2048]
                                            const float* __restrict__ att,           // [4][256]
                                            const int* __restrict__ offsets,
                                            const int* __restrict__ esrc,
                                            const float* __restrict__ bias,          // [256]
                                            unsigned short* __restrict__ outH,
                                            unsigned short* __restrict__ outL,
                                            int N) {
    __shared__ float accLds[4][256];
    const int t = threadIdx.x;
    const int wv = t >> 6, lane = t & 63;
    const int n = blockIdx.x;

    if (n >= N) {   // zero-pad rows for downstream MFMA GEMM
        int c = t * 2;
        *(ushort2*)&outH[(size_t)n * 256 + c] = make_ushort2(0, 0);
        *(ushort2*)&outL[(size_t)n * 256 + c] = make_ushort2(0, 0);
        return;
    }

    const int eoff = 512 * wv + lane * 8;   // element offset within xl row (0..1023)
    const int h = eoff >> 8;                // head 0..3
    const int gl = lane & 31;               // 8-channel group within head

    float a[8];
    {
        const float* pa = att + h * 256 + gl * 8;
        float4 a0 = *(const float4*)pa, a1 = *(const float4*)(pa + 4);
        a[0] = a0.x; a[1] = a0.y; a[2] = a0.z; a[3] = a0.w;
        a[4] = a1.x; a[5] = a1.y; a[6] = a1.z; a[7] = a1.w;
    }
    float r[8];
    {
        u16x8 u = *(const u16x8*)(xlr + (size_t)n * 2048 + 1024 + eoff);
#pragma unroll
        for (int v = 0; v < 8; ++v) r[v] = bf2f(u[v]);
    }
    int o0 = offsets[n];
    int deg = offsets[n + 1] - o0;

    float acc[8];
#pragma unroll
    for (int v = 0; v < 8; ++v) acc[v] = 0.f;
    float s = 0.f;

    for (int j = 0; j < deg; j += 2) {
        int e0 = esrc[o0 + j];
        bool has1 = (j + 1) < deg;
        int e1 = esrc[o0 + (has1 ? j + 1 : j)];
        u16x8 g0 = *(const u16x8*)(xlr + (size_t)e0 * 2048 + eoff);
        u16x8 g1 = *(const u16x8*)(xlr + (size_t)e1 * 2048 + eoff);
        float x0[8], x1[8];
#pragma unroll
        for (int v = 0; v < 8; ++v) { x0[v] = bf2f(g0[v]); x1[v] = bf2f(g1[v]); }
        float q0 = 0.f, q1 = 0.f;
#pragma unroll
        for (int v = 0; v < 8; ++v) {
            q0 += a[v] * lrelu(x0[v] + r[v]);
            q1 += a[v] * lrelu(x1[v] + r[v]);
        }
#pragma unroll
        for (int m = 1; m < 32; m <<= 1) {   // reduce within 32-lane half (one head)
            q0 += __shfl_xor(q0, m);
            q1 += __shfl_xor(q1, m);
        }
        q0 = fminf(fmaxf(q0, -60.f), 60.f);
        q1 = fminf(fmaxf(q1, -60.f), 60.f);
        float w0 = __expf(q0);
        float w1 = has1 ? __expf(q1) : 0.f;
        s += w0 + w1;
#pragma unroll
        for (int v = 0; v < 8; ++v) acc[v] += w0 * x0[v] + w1 * x1[v];
    }

    float inv = 1.0f / s;   // s identical across the 32-lane half
#pragma unroll
    for (int v = 0; v < 8; ++v) accLds[h][gl * 8 + v] = acc[v] * inv;
    __syncthreads();

    {   // head-mean + bias + lrelu + hi/lo split; thread t owns channels t, t+128
        int c0 = t, c1 = t + 128;
        float v0 = (accLds[0][c0] + accLds[1][c0] + accLds[2][c0] + accLds[3][c0]) * 0.25f + bias[c0];
        float v1 = (accLds[0][c1] + accLds[1][c1] + accLds[2][c1] + accLds[3][c1]) * 0.25f + bias[c1];
        v0 = lrelu(v0); v1 = lrelu(v1);
        unsigned short h0 = f2bf_rne(v0), h1v = f2bf_rne(v1);
        outH[(size_t)n * 256 + c0] = h0;
        outH[(size_t)n * 256 + c1] = h1v;
        outL[(size_t)n * 256 + c0] = f2bf_rne(v0 - bf2f(h0));
        outL[(size_t)n * 256 + c1] = f2bf_rne(v1 - bf2f(h1v));
    }
}

// ---------------- layer-2 fused aggregate: one wave per node ----------------
// Wave's 64 lanes cover the whole 1KB xl row (all 4 heads) in ONE contiguous
// load. Logit reduce = 4 shfl in 16-lane groups; head-mean via shfl 16/32.
// No LDS, no syncthreads. 4 nodes per 256-thread block.
__global__ __launch_bounds__(256) void agg2(const unsigned short* __restrict__ xlr,  // [N][1024]
                                            const float* __restrict__ att,           // [4][128]
                                            const int* __restrict__ offsets,
                                            const int* __restrict__ esrc,
                                            const float* __restrict__ bias,          // [128]
                                            float* __restrict__ out, int N) {
    const int lane = threadIdx.x & 63;
    const int n = blockIdx.x * 4 + (threadIdx.x >> 6);
    if (n >= N) return;
    const int h = lane >> 4, gl = lane & 15;
    const int eoff = lane * 8;   // element offset within xl row (0..511)

    float a[8], bs[8];
    {
        const float* pa = att + h * 128 + gl * 8;
        float4 a0 = *(const float4*)pa, a1 = *(const float4*)(pa + 4);
        a[0] = a0.x; a[1] = a0.y; a[2] = a0.z; a[3] = a0.w;
        a[4] = a1.x; a[5] = a1.y; a[6] = a1.z; a[7] = a1.w;
        const float* pb = bias + gl * 8;
        float4 b0 = *(const float4*)pb, b1v = *(const float4*)(pb + 4);
        bs[0] = b0.x; bs[1] = b0.y; bs[2] = b0.z; bs[3] = b0.w;
        bs[4] = b1v.x; bs[5] = b1v.y; bs[6] = b1v.z; bs[7] = b1v.w;
    }
    float r[8];
    {
        u16x8 u = *(const u16x8*)(xlr + (size_t)n * 1024 + 512 + eoff);
#pragma unroll
        for (int v = 0; v < 8; ++v) r[v] = bf2f(u[v]);
    }
    int o0 = offsets[n];
    int deg = offsets[n + 1] - o0;

    float acc[8];
#pragma unroll
    for (int v = 0; v < 8; ++v) acc[v] = 0.f;
    float s = 0.f;

    for (int j = 0; j < deg; j += 2) {
        int e0 = esrc[o0 + j];
        bool has1 = (j + 1) < deg;
        int e1 = esrc[o0 + (has1 ? j + 1 : j)];
        u16x8 g0 = *(const u16x8*)(xlr + (size_t)e0 * 1024 + eoff);
        u16x8 g1 = *(const u16x8*)(xlr + (size_t)e1 * 1024 + eoff);
        float x0[8], x1[8];
#pragma unroll
        for (int v = 0; v < 8; ++v) { x0[v] = bf2f(g0[v]); x1[v] = bf2f(g1[v]); }
        float q0 = 0.f, q1 = 0.f;
#pragma unroll
        for (int v = 0; v < 8; ++v) {
            q0 += a[v] * lrelu(x0[v] + r[v]);
            q1 += a[v] * lrelu(x1[v] + r[v]);
        }
#pragma unroll
        for (int m = 1; m < 16; m <<= 1) {   // reduce within 16-lane group (one head)
            q0 += __shfl_xor(q0, m);
            q1 += __shfl_xor(q1, m);
        }
        q0 = fminf(fmaxf(q0, -60.f), 60.f);
        q1 = fminf(fmaxf(q1, -60.f), 60.f);
        float w0 = __expf(q0);
        float w1 = has1 ? __expf(q1) : 0.f;
        s += w0 + w1;
#pragma unroll
        for (int v = 0; v < 8; ++v) acc[v] += w0 * x0[v] + w1 * x1[v];
    }

    float inv = 1.0f / s;
#pragma unroll
    for (int v = 0; v < 8; ++v) acc[v] *= inv;
    // head-mean: normalize first, then cross-group sum
#pragma unroll
    for (int v = 0; v < 8; ++v) {
        acc[v] += __shfl_xor(acc[v], 16);
        acc[v] += __shfl_xor(acc[v], 32);
    }
    if (h == 0) {
        float o[8];
#pragma unroll
        for (int v = 0; v < 8; ++v) o[v] = tanhf(acc[v] * 0.25f + bs[v]);
        float* po = out + (size_t)n * 128 + gl * 8;
        *(float4*)po = make_float4(o[0], o[1], o[2], o[3]);
        *(float4*)(po + 4) = make_float4(o[4], o[5], o[6], o[7]);
    }
}

// ---------------- launch ----------------

extern "C" void kernel_launch(void* const* d_in, const int* in_sizes, int n_in,
                              void* d_out, int out_size, void* d_ws, size_t ws_size,
                              hipStream_t stream) {
    const float* x    = (const float*)d_in[0];
    const int*   ei   = (const int*)d_in[1];
    const float* Wl1  = (const float*)d_in[2];
    const float* Wr1  = (const float*)d_in[3];
    const float* att1 = (const float*)d_in[4];
    const float* b1   = (const float*)d_in[5];
    const float* Wl2  = (const float*)d_in[6];
    const float* Wr2  = (const float*)d_in[7];
    const float* att2 = (const float*)d_in[8];
    const float* b2   = (const float*)d_in[9];
    float* out = (float*)d_out;

    const int IN = 512, HID = 256, OUT = 128, H = 4;
    int N  = in_sizes[0] / IN;
    int E  = in_sizes[1] / 2;
    int ET = E + N;
    int M2 = ((N + 127) / 128) * 128;   // 10112

    char* w = (char*)d_ws;
    auto carve = [&](size_t bytes) {
        char* p = w;
        w += (bytes + 255) & ~(size_t)255;
        return (void*)p;
    };
    unsigned short* x_hi = (unsigned short*)carve((size_t)M2 * IN * 2);
    unsigned short* xlr1 = (unsigned short*)carve((size_t)N * 2 * H * HID * 2);
    unsigned short* BT1 = (unsigned short*)carve((size_t)(2 * H * HID) * IN * 2);
    int* src     = (int*)carve((size_t)ET * 4);
    int* dst     = (int*)carve((size_t)ET * 4);
    int* counts  = (int*)carve((size_t)N * 4);
    int* cursor  = (int*)carve((size_t)N * 4);
    int* offsets = (int*)carve((size_t)(N + 1) * 4);
    int* esrc    = (int*)carve((size_t)ET * 4);
    unsigned short* h1_h = x_hi;
    unsigned short* h1_l = x_hi + (size_t)M2 * HID;
    unsigned short* xlr2 = xlr1;
    unsigned short* BT2  = BT1;

    // ---- CSR build ----
    hipMemsetAsync(counts, 0, (size_t)((char*)offsets - (char*)counts), stream);
    build_edges<<<(ET + 255) / 256, 256, 0, stream>>>(ei, E, N, src, dst, counts);
    scan_offsets<<<1, 1024, 0, stream>>>(counts, offsets, N);
    fill_eids<<<(ET + 255) / 256, 256, 0, stream>>>(src, dst, offsets, cursor, esrc, ET);

    // ---- prep layer 1 ----
    {
        int total4 = M2 * IN / 4;
        conv_hi<<<(total4 + 255) / 256, 256, 0, stream>>>(x, x_hi, N, 9, total4);
        thi<<<dim3((H * HID) / 32, IN / 32), dim3(32, 8), 0, stream>>>(Wl1, BT1, IN, H * HID);
        thi<<<dim3((H * HID) / 32, IN / 32), dim3(32, 8), 0, stream>>>(Wr1, BT1 + (size_t)(H * HID) * IN, IN, H * HID);
    }
    // ---- layer 1 GEMM (combined Wl|Wr, pure bf16, bf16 out) ----
    {
        dim3 g((2 * H * HID) / 128, M2 / 128);
        gemm_mfma<1, true><<<g, 256, 0, stream>>>(x_hi, nullptr, BT1, nullptr, xlr1, N, 2 * H * HID, IN);
    }
    // ---- layer 1 aggregate: block per node, contiguous 1KB gathers ----
    agg1<<<M2, 128, 0, stream>>>(xlr1, att1, offsets, esrc, b1, h1_h, h1_l, N);
    // ---- prep layer 2 ----
    thi<<<dim3((H * OUT) / 32, HID / 32), dim3(32, 8), 0, stream>>>(Wl2, BT2, HID, H * OUT);
    thi<<<dim3((H * OUT) / 32, HID / 32), dim3(32, 8), 0, stream>>>(Wr2, BT2 + (size_t)(H * OUT) * HID, HID, H * OUT);
    // ---- layer 2 GEMM (combined, 2-term, bf16 out) ----
    {
        dim3 g((2 * H * OUT) / 128, M2 / 128);
        gemm_mfma<2, true><<<g, 256, 0, stream>>>(h1_h, h1_l, BT2, nullptr, xlr2, N, 2 * H * OUT, HID);
    }
    // ---- layer 2 aggregate: wave per node, one contiguous 1KB gather ----
    agg2<<<(N + 3) / 4, 256, 0, stream>>>(xlr2, att2, offsets, esrc, b2, out, N);
}

// Round 13
// 171.172 us; speedup vs baseline: 1.0900x; 1.0854x over previous
//
#include <hip/hip_runtime.h>
#include <hip/hip_bf16.h>
#include <math.h>

#define DEVINL __device__ __forceinline__

typedef __attribute__((ext_vector_type(8))) short bf16x8;
typedef __attribute__((ext_vector_type(8))) unsigned short u16x8;
typedef __attribute__((ext_vector_type(4))) float f32x4;
typedef __attribute__((ext_vector_type(2))) float f32x2;

DEVINL float lrelu(float x) { return x > 0.f ? x : 0.2f * x; }

DEVINL unsigned short f2bf_rne(float f) {
    unsigned u = __float_as_uint(f);
    unsigned r = u + 0x7fff + ((u >> 16) & 1);
    return (unsigned short)(r >> 16);
}
DEVINL float bf2f(unsigned short h) { return __uint_as_float(((unsigned)h) << 16); }

// unpack 2 bf16 (packed in one u32) -> f32x2
DEVINL f32x2 bf2f2(unsigned u) {
    f32x2 r;
    r.x = __uint_as_float(u << 16);
    r.y = __uint_as_float(u & 0xffff0000u);
    return r;
}

// VALU-only 16-lane-row rotate-add step (DPP row_ror:N); 4 steps => row sum in all 16 lanes
template <int CTRL>
DEVINL float dppadd(float x) {
    return x + __int_as_float(__builtin_amdgcn_update_dpp(
        0, __float_as_int(x), CTRL, 0xF, 0xF, false));
}
DEVINL float rowsum16(float x) {
    x = dppadd<0x121>(x);   // row_ror:1
    x = dppadd<0x122>(x);   // row_ror:2
    x = dppadd<0x124>(x);   // row_ror:4
    x = dppadd<0x128>(x);   // row_ror:8
    return x;
}

DEVINL void gload_lds16(const void* g, void* l) {
    __builtin_amdgcn_global_load_lds(
        (const __attribute__((address_space(1))) void*)g,
        (__attribute__((address_space(3))) void*)l, 16, 0, 0);
}

// ---------------- CSR build ----------------

__global__ void build_edges(const int* __restrict__ ei, int E, int N,
                            int* __restrict__ src, int* __restrict__ dst,
                            int* __restrict__ counts) {
    int e = blockIdx.x * 256 + threadIdx.x;
    int ET = E + N;
    if (e >= ET) return;
    int s, d;
    if (e < E) { s = ei[e]; d = ei[E + e]; }
    else       { s = d = e - E; }
    s = min(max(s, 0), N - 1);
    d = min(max(d, 0), N - 1);
    src[e] = s;
    dst[e] = d;
    atomicAdd(&counts[d], 1);
}

__global__ void scan_offsets(const int* __restrict__ counts, int* __restrict__ offsets, int N) {
    const int T = 1024;
    __shared__ int sums[T];
    int t = threadIdx.x;
    int chunk = (N + T - 1) / T;
    int base = t * chunk;
    int local[16];
    int s = 0;
    for (int i = 0; i < chunk; ++i) {
        int v = (base + i < N) ? counts[base + i] : 0;
        local[i] = s;
        s += v;
    }
    sums[t] = s;
    __syncthreads();
    for (int d = 1; d < T; d <<= 1) {
        int v = (t >= d) ? sums[t - d] : 0;
        __syncthreads();
        sums[t] += v;
        __syncthreads();
    }
    int excl = (t == 0) ? 0 : sums[t - 1];
    for (int i = 0; i < chunk; ++i)
        if (base + i < N) offsets[base + i] = excl + local[i];
    if (t == T - 1) offsets[N] = excl + s;
}

__global__ void fill_eids(const int* __restrict__ src, const int* __restrict__ dst,
                          const int* __restrict__ offsets,
                          int* __restrict__ cursor, int* __restrict__ esrc, int ET) {
    int e = blockIdx.x * 256 + threadIdx.x;
    if (e >= ET) return;
    int d = dst[e];
    int pos = offsets[d] + atomicAdd(&cursor[d], 1);
    esrc[pos] = src[e];
}

// ---------------- f32 -> hi bf16 (RNE), zero-padded rows >= M ----------------
__global__ void conv_hi(const float* __restrict__ x, unsigned short* __restrict__ hi,
                        int M, int log2K, int total4) {
    int i = blockIdx.x * 256 + threadIdx.x;
    if (i >= total4) return;
    int e = i * 4;
    int row = e >> log2K;
    ushort4 vh = make_ushort4(0, 0, 0, 0);
    if (row < M) {
        float4 v = *(const float4*)&x[e];
        vh = make_ushort4(f2bf_rne(v.x), f2bf_rne(v.y), f2bf_rne(v.z), f2bf_rne(v.w));
    }
    *(ushort4*)&hi[e] = vh;
}

// ---------------- W[K][Nout] f32 -> BT[Nout][K] hi bf16; blockIdx.z picks W0/W1 ----------------
__global__ void thi2(const float* __restrict__ W0, const float* __restrict__ W1,
                     unsigned short* __restrict__ BT, int K, int Nout) {
    __shared__ float tile[32][33];
    const float* W = blockIdx.z ? W1 : W0;
    unsigned short* out = BT + (size_t)blockIdx.z * Nout * K;
    int n0 = blockIdx.x * 32, k0 = blockIdx.y * 32;
    int tx = threadIdx.x, ty = threadIdx.y;
#pragma unroll
    for (int i = 0; i < 4; ++i)
        tile[ty + 8 * i][tx] = W[(size_t)(k0 + ty + 8 * i) * Nout + n0 + tx];
    __syncthreads();
#pragma unroll
    for (int i = 0; i < 4; ++i) {
        int r = ty + 8 * i;
        out[(size_t)(n0 + r) * K + k0 + tx] = f2bf_rne(tile[tx][r]);
    }
}

// ---------------- bf16 MFMA GEMM: C[M][Nout] = A[M2][K] @ BT[Nout][K]^T ----------------
// 128x128 tile, BK=64, 4 waves (2x2), 16x16x32 bf16 MFMA, T1 bijective XCD swizzle.
template <int TERMS, bool OUTBF16>
__global__ __launch_bounds__(256) void gemm_mfma(
    const unsigned short* __restrict__ Ah, const unsigned short* __restrict__ Al,
    const unsigned short* __restrict__ Bh,
    float* __restrict__ Cf, unsigned short* __restrict__ Cb,
    int M, int Nout, int K) {
    constexpr int BOFF = (TERMS == 2) ? 32768 : 16384;
    __shared__ __align__(16) char lds[BOFF + 16384];
    const int t = threadIdx.x;
    const int L = t & 63, w = t >> 6;
    const int wm = w & 1, wn = w >> 1;
    const int nwg = gridDim.x * gridDim.y;
    int orig = blockIdx.y * gridDim.x + blockIdx.x;
    int q = nwg >> 3, rr = nwg & 7;
    int xcd = orig & 7, pos = orig >> 3;
    int wg = (xcd < rr ? xcd * (q + 1) : rr * (q + 1) + (xcd - rr) * q) + pos;
    const int bm = (wg / gridDim.x) * 128, bn = (wg % gridDim.x) * 128;
    const size_t strideA = (size_t)K * 2;

    const f32x4 vzero = {0.f, 0.f, 0.f, 0.f};
    f32x4 acc[4][4];
#pragma unroll
    for (int i = 0; i < 4; ++i)
#pragma unroll
        for (int j = 0; j < 4; ++j) acc[i][j] = vzero;

    for (int k0 = 0; k0 < K; k0 += 64) {
#pragma unroll
        for (int i = 0; i < 4; ++i) {
            int slot = i * 256 + t;
            int offs = slot * 16;
            int r = offs >> 7;
            int cb = (offs & 127) ^ ((r & 7) << 4);
            size_t gofs = (size_t)r * strideA + (size_t)k0 * 2 + cb;
            gload_lds16((const char*)Ah + (size_t)bm * strideA + gofs, lds + offs);
            if constexpr (TERMS == 2)
                gload_lds16((const char*)Al + (size_t)bm * strideA + gofs, lds + 16384 + offs);
            gload_lds16((const char*)Bh + (size_t)bn * strideA + gofs, lds + BOFF + offs);
        }
        __syncthreads();
#pragma unroll
        for (int kf = 0; kf < 2; ++kf) {
            const int kb = kf * 64 + ((L >> 4) * 16);
            bf16x8 ah[4], al[4], bh[4];
#pragma unroll
            for (int mi = 0; mi < 4; ++mi) {
                int r = wm * 64 + mi * 16 + (L & 15);
                int off = r * 128 + (kb ^ ((r & 7) << 4));
                ah[mi] = *(const bf16x8*)(lds + off);
                if constexpr (TERMS == 2) al[mi] = *(const bf16x8*)(lds + 16384 + off);
            }
#pragma unroll
            for (int ni = 0; ni < 4; ++ni) {
                int r = wn * 64 + ni * 16 + (L & 15);
                int off = r * 128 + (kb ^ ((r & 7) << 4));
                bh[ni] = *(const bf16x8*)(lds + BOFF + off);
            }
#pragma unroll
            for (int mi = 0; mi < 4; ++mi)
#pragma unroll
                for (int ni = 0; ni < 4; ++ni) {
                    acc[mi][ni] = __builtin_amdgcn_mfma_f32_16x16x32_bf16(ah[mi], bh[ni], acc[mi][ni], 0, 0, 0);
                    if constexpr (TERMS == 2)
                        acc[mi][ni] = __builtin_amdgcn_mfma_f32_16x16x32_bf16(al[mi], bh[ni], acc[mi][ni], 0, 0, 0);
                }
        }
        __syncthreads();
    }
    const int colBase = bn + wn * 64 + (L & 15);
#pragma unroll
    for (int mi = 0; mi < 4; ++mi) {
        int row0 = bm + wm * 64 + mi * 16 + (L >> 4) * 4;
#pragma unroll
        for (int j = 0; j < 4; ++j) {
            int row = row0 + j;
            if (row < M) {
#pragma unroll
                for (int ni = 0; ni < 4; ++ni) {
                    if constexpr (OUTBF16)
                        Cb[(size_t)row * Nout + colBase + ni * 16] = f2bf_rne(acc[mi][ni][j]);
                    else
                        Cf[(size_t)row * Nout + colBase + ni * 16] = acc[mi][ni][j];
                }
            }
        }
    }
}

// ---------------- layer-1 fused aggregate: 256-thread block = 2 nodes ----------------
// Per node: 2 waves; wave wv covers heads 2wv,2wv+1 (contiguous 1KB per gather,
// 16B/lane). Edge indices scalarized (readfirstlane -> SGPR base, saddr loads).
// Logit math on f32x2 (packed-f32); in-loop reduce = 4 DPP row_ror adds +
// one shfl_xor(16). Head-merge via LDS; bias+lrelu+hi/lo split write.
__global__ __launch_bounds__(256) void agg1(const unsigned short* __restrict__ xlr,  // [M2][2048]
                                            const float* __restrict__ att,           // [4][256]
                                            const int* __restrict__ offsets,
                                            const int* __restrict__ esrc,
                                            const float* __restrict__ bias,          // [256]
                                            unsigned short* __restrict__ outH,
                                            unsigned short* __restrict__ outL,
                                            int N) {
    __shared__ float accLds[2][4][256];
    const int t = threadIdx.x;
    const int half = t >> 7;             // node slot within block
    const int ht = t & 127;
    const int wv = ht >> 6, lane = ht & 63;
    const int n = blockIdx.x * 2 + half;

    if (blockIdx.x * 2 >= N) {           // all-pad block (N even -> boundary aligned)
        int c = ht * 2;
        *(ushort2*)&outH[(size_t)n * 256 + c] = make_ushort2(0, 0);
        *(ushort2*)&outL[(size_t)n * 256 + c] = make_ushort2(0, 0);
        return;
    }

    const int eoff = 512 * wv + lane * 8;   // element offset in xl row [0,1024)
    const int h = eoff >> 8;                // head 0..3
    const int gl = lane & 31;

    f32x2 a2[4], r2[4];
    {
        const float* pa = att + h * 256 + gl * 8;
#pragma unroll
        for (int p = 0; p < 4; ++p) { a2[p].x = pa[2 * p]; a2[p].y = pa[2 * p + 1]; }
        const uint4 u = *(const uint4*)(xlr + (size_t)n * 2048 + 1024 + eoff);
        r2[0] = bf2f2(u.x); r2[1] = bf2f2(u.y); r2[2] = bf2f2(u.z); r2[3] = bf2f2(u.w);
    }
    const int o0  = __builtin_amdgcn_readfirstlane(offsets[n]);
    const int deg = __builtin_amdgcn_readfirstlane(offsets[n + 1]) - o0;

    f32x2 acc2[4];
#pragma unroll
    for (int p = 0; p < 4; ++p) acc2[p] = (f32x2){0.f, 0.f};
    float s = 0.f;

    for (int j = 0; j < deg; j += 2) {
        int e0 = __builtin_amdgcn_readfirstlane(esrc[o0 + j]);
        bool has1 = (j + 1) < deg;
        int e1 = __builtin_amdgcn_readfirstlane(esrc[o0 + (has1 ? j + 1 : j)]);
        const unsigned short* row0 = xlr + (size_t)e0 * 2048;   // SGPR base
        const unsigned short* row1 = xlr + (size_t)e1 * 2048;
        uint4 g0 = *(const uint4*)(row0 + eoff);
        uint4 g1 = *(const uint4*)(row1 + eoff);
        f32x2 x0[4], x1[4];
        x0[0] = bf2f2(g0.x); x0[1] = bf2f2(g0.y); x0[2] = bf2f2(g0.z); x0[3] = bf2f2(g0.w);
        x1[0] = bf2f2(g1.x); x1[1] = bf2f2(g1.y); x1[2] = bf2f2(g1.z); x1[3] = bf2f2(g1.w);
        f32x2 q02 = {0.f, 0.f}, q12 = {0.f, 0.f};
#pragma unroll
        for (int p = 0; p < 4; ++p) {
            f32x2 t0 = x0[p] + r2[p];
            f32x2 t1 = x1[p] + r2[p];
            f32x2 m0 = t0 * 0.2f;
            f32x2 m1 = t1 * 0.2f;
            f32x2 u0, u1;
            u0.x = fmaxf(t0.x, m0.x); u0.y = fmaxf(t0.y, m0.y);
            u1.x = fmaxf(t1.x, m1.x); u1.y = fmaxf(t1.y, m1.y);
            q02 += a2[p] * u0;
            q12 += a2[p] * u1;
        }
        float q0 = q02.x + q02.y;
        float q1 = q12.x + q12.y;
        q0 = rowsum16(q0); q0 += __shfl_xor(q0, 16);
        q1 = rowsum16(q1); q1 += __shfl_xor(q1, 16);
        q0 = fminf(fmaxf(q0, -60.f), 60.f);
        q1 = fminf(fmaxf(q1, -60.f), 60.f);
        float w0 = __expf(q0);
        float w1 = has1 ? __expf(q1) : 0.f;
        s += w0 + w1;
        f32x2 w02 = {w0, w0}, w12 = {w1, w1};
#pragma unroll
        for (int p = 0; p < 4; ++p) acc2[p] += x0[p] * w02 + x1[p] * w12;
    }

    float inv = 1.0f / s;   // uniform within 32-lane half
    {
        float* dst = &accLds[half][h][gl * 8];
#pragma unroll
        for (int p = 0; p < 4; ++p) {
            dst[2 * p]     = acc2[p].x * inv;
            dst[2 * p + 1] = acc2[p].y * inv;
        }
    }
    __syncthreads();

    {   // head-mean + bias + lrelu + hi/lo split; thread owns channels 2ht, 2ht+1 of its node
        int c = ht * 2;
        float v0 = (accLds[half][0][c] + accLds[half][1][c] + accLds[half][2][c] + accLds[half][3][c]) * 0.25f + bias[c];
        float v1 = (accLds[half][0][c + 1] + accLds[half][1][c + 1] + accLds[half][2][c + 1] + accLds[half][3][c + 1]) * 0.25f + bias[c + 1];
        v0 = lrelu(v0); v1 = lrelu(v1);
        unsigned short h0 = f2bf_rne(v0), h1v = f2bf_rne(v1);
        *(ushort2*)&outH[(size_t)n * 256 + c] = make_ushort2(h0, h1v);
        *(ushort2*)&outL[(size_t)n * 256 + c] =
            make_ushort2(f2bf_rne(v0 - bf2f(h0)), f2bf_rne(v1 - bf2f(h1v)));
    }
}

// ---------------- layer-2 fused aggregate: one wave per node ----------------
// 64 lanes cover the whole 1KB row (16-lane group per head, aligned to DPP rows).
// In-loop reduce = 4 DPP adds (pure VALU). Head-mean via shfl 16/32 at the end.
__global__ __launch_bounds__(256) void agg2(const unsigned short* __restrict__ xlr,  // [N][1024]
                                            const float* __restrict__ att,           // [4][128]
                                            const int* __restrict__ offsets,
                                            const int* __restrict__ esrc,
                                            const float* __restrict__ bias,          // [128]
                                            float* __restrict__ out, int N) {
    const int lane = threadIdx.x & 63;
    const int n = blockIdx.x * 4 + (threadIdx.x >> 6);
    if (n >= N) return;
    const int h = lane >> 4, gl = lane & 15;
    const int eoff = lane * 8;

    f32x2 a2[4], bs2[4], r2[4];
    {
        const float* pa = att + h * 128 + gl * 8;
        const float* pb = bias + gl * 8;
#pragma unroll
        for (int p = 0; p < 4; ++p) {
            a2[p].x = pa[2 * p];  a2[p].y = pa[2 * p + 1];
            bs2[p].x = pb[2 * p]; bs2[p].y = pb[2 * p + 1];
        }
        const uint4 u = *(const uint4*)(xlr + (size_t)n * 1024 + 512 + eoff);
        r2[0] = bf2f2(u.x); r2[1] = bf2f2(u.y); r2[2] = bf2f2(u.z); r2[3] = bf2f2(u.w);
    }
    const int o0  = __builtin_amdgcn_readfirstlane(offsets[n]);
    const int deg = __builtin_amdgcn_readfirstlane(offsets[n + 1]) - o0;

    f32x2 acc2[4];
#pragma unroll
    for (int p = 0; p < 4; ++p) acc2[p] = (f32x2){0.f, 0.f};
    float s = 0.f;

    for (int j = 0; j < deg; j += 2) {
        int e0 = __builtin_amdgcn_readfirstlane(esrc[o0 + j]);
        bool has1 = (j + 1) < deg;
        int e1 = __builtin_amdgcn_readfirstlane(esrc[o0 + (has1 ? j + 1 : j)]);
        const unsigned short* row0 = xlr + (size_t)e0 * 1024;
        const unsigned short* row1 = xlr + (size_t)e1 * 1024;
        uint4 g0 = *(const uint4*)(row0 + eoff);
        uint4 g1 = *(const uint4*)(row1 + eoff);
        f32x2 x0[4], x1[4];
        x0[0] = bf2f2(g0.x); x0[1] = bf2f2(g0.y); x0[2] = bf2f2(g0.z); x0[3] = bf2f2(g0.w);
        x1[0] = bf2f2(g1.x); x1[1] = bf2f2(g1.y); x1[2] = bf2f2(g1.z); x1[3] = bf2f2(g1.w);
        f32x2 q02 = {0.f, 0.f}, q12 = {0.f, 0.f};
#pragma unroll
        for (int p = 0; p < 4; ++p) {
            f32x2 t0 = x0[p] + r2[p];
            f32x2 t1 = x1[p] + r2[p];
            f32x2 m0 = t0 * 0.2f;
            f32x2 m1 = t1 * 0.2f;
            f32x2 u0, u1;
            u0.x = fmaxf(t0.x, m0.x); u0.y = fmaxf(t0.y, m0.y);
            u1.x = fmaxf(t1.x, m1.x); u1.y = fmaxf(t1.y, m1.y);
            q02 += a2[p] * u0;
            q12 += a2[p] * u1;
        }
        float q0 = rowsum16(q02.x + q02.y);   // head group == DPP row
        float q1 = rowsum16(q12.x + q12.y);
        q0 = fminf(fmaxf(q0, -60.f), 60.f);
        q1 = fminf(fmaxf(q1, -60.f), 60.f);
        float w0 = __expf(q0);
        float w1 = has1 ? __expf(q1) : 0.f;
        s += w0 + w1;
        f32x2 w02 = {w0, w0}, w12 = {w1, w1};
#pragma unroll
        for (int p = 0; p < 4; ++p) acc2[p] += x0[p] * w02 + x1[p] * w12;
    }

    float inv = 1.0f / s;
#pragma unroll
    for (int p = 0; p < 4; ++p) {
        acc2[p].x *= inv; acc2[p].y *= inv;
        acc2[p].x += __shfl_xor(acc2[p].x, 16);
        acc2[p].x += __shfl_xor(acc2[p].x, 32);
        acc2[p].y += __shfl_xor(acc2[p].y, 16);
        acc2[p].y += __shfl_xor(acc2[p].y, 32);
    }
    if (h == 0) {
        float o[8];
#pragma unroll
        for (int p = 0; p < 4; ++p) {
            o[2 * p]     = tanhf(acc2[p].x * 0.25f + bs2[p].x);
            o[2 * p + 1] = tanhf(acc2[p].y * 0.25f + bs2[p].y);
        }
        float* po = out + (size_t)n * 128 + gl * 8;
        *(float4*)po = make_float4(o[0], o[1], o[2], o[3]);
        *(float4*)(po + 4) = make_float4(o[4], o[5], o[6], o[7]);
    }
}

// ---------------- launch ----------------

extern "C" void kernel_launch(void* const* d_in, const int* in_sizes, int n_in,
                              void* d_out, int out_size, void* d_ws, size_t ws_size,
                              hipStream_t stream) {
    const float* x    = (const float*)d_in[0];
    const int*   ei   = (const int*)d_in[1];
    const float* Wl1  = (const float*)d_in[2];
    const float* Wr1  = (const float*)d_in[3];
    const float* att1 = (const float*)d_in[4];
    const float* b1   = (const float*)d_in[5];
    const float* Wl2  = (const float*)d_in[6];
    const float* Wr2  = (const float*)d_in[7];
    const float* att2 = (const float*)d_in[8];
    const float* b2   = (const float*)d_in[9];
    float* out = (float*)d_out;

    const int IN = 512, HID = 256, OUT = 128, H = 4;
    int N  = in_sizes[0] / IN;
    int E  = in_sizes[1] / 2;
    int ET = E + N;
    int M2 = ((N + 127) / 128) * 128;   // 10112

    char* w = (char*)d_ws;
    auto carve = [&](size_t bytes) {
        char* p = w;
        w += (bytes + 255) & ~(size_t)255;
        return (void*)p;
    };
    unsigned short* x_hi = (unsigned short*)carve((size_t)M2 * IN * 2);
    unsigned short* xlr1 = (unsigned short*)carve((size_t)N * 2 * H * HID * 2);
    unsigned short* BT1 = (unsigned short*)carve((size_t)(2 * H * HID) * IN * 2);
    int* src     = (int*)carve((size_t)ET * 4);
    int* dst     = (int*)carve((size_t)ET * 4);
    int* counts  = (int*)carve((size_t)N * 4);
    int* cursor  = (int*)carve((size_t)N * 4);
    int* offsets = (int*)carve((size_t)(N + 1) * 4);
    int* esrc    = (int*)carve((size_t)ET * 4);
    unsigned short* h1_h = x_hi;
    unsigned short* h1_l = x_hi + (size_t)M2 * HID;
    unsigned short* xlr2 = xlr1;
    unsigned short* BT2  = BT1;

    // ---- CSR build ----
    hipMemsetAsync(counts, 0, (size_t)((char*)offsets - (char*)counts), stream);
    build_edges<<<(ET + 255) / 256, 256, 0, stream>>>(ei, E, N, src, dst, counts);
    scan_offsets<<<1, 1024, 0, stream>>>(counts, offsets, N);
    fill_eids<<<(ET + 255) / 256, 256, 0, stream>>>(src, dst, offsets, cursor, esrc, ET);

    // ---- prep layer 1 ----
    {
        int total4 = M2 * IN / 4;
        conv_hi<<<(total4 + 255) / 256, 256, 0, stream>>>(x, x_hi, N, 9, total4);
        thi2<<<dim3((H * HID) / 32, IN / 32, 2), dim3(32, 8), 0, stream>>>(Wl1, Wr1, BT1, IN, H * HID);
    }
    // ---- layer 1 GEMM (combined Wl|Wr, pure bf16, bf16 out) ----
    {
        dim3 g((2 * H * HID) / 128, M2 / 128);
        gemm_mfma<1, true><<<g, 256, 0, stream>>>(x_hi, nullptr, BT1, nullptr, xlr1, N, 2 * H * HID, IN);
    }
    // ---- layer 1 aggregate: 2 nodes per block ----
    agg1<<<M2 / 2, 256, 0, stream>>>(xlr1, att1, offsets, esrc, b1, h1_h, h1_l, N);
    // ---- prep layer 2 ----
    thi2<<<dim3((H * OUT) / 32, HID / 32, 2), dim3(32, 8), 0, stream>>>(Wl2, Wr2, BT2, HID, H * OUT);
    // ---- layer 2 GEMM (combined, 2-term, bf16 out) ----
    {
        dim3 g((2 * H * OUT) / 128, M2 / 128);
        gemm_mfma<2, true><<<g, 256, 0, stream>>>(h1_h, h1_l, BT2, nullptr, xlr2, N, 2 * H * OUT, HID);
    }
    // ---- layer 2 aggregate: wave per node ----
    agg2<<<(N + 3) / 4, 256, 0, stream>>>(xlr2, att2, offsets, esrc, b2, out, N);
}

// Round 14
// 169.446 us; speedup vs baseline: 1.1011x; 1.0102x over previous
//
#include <hip/hip_runtime.h>
#include <hip/hip_bf16.h>
#include <math.h>

#define DEVINL __device__ __forceinline__

typedef __attribute__((ext_vector_type(8))) short bf16x8;
typedef __attribute__((ext_vector_type(8))) unsigned short u16x8;
typedef __attribute__((ext_vector_type(4))) float f32x4;
typedef __attribute__((ext_vector_type(2))) float f32x2;

DEVINL float lrelu(float x) { return x > 0.f ? x : 0.2f * x; }

DEVINL unsigned short f2bf_rne(float f) {
    unsigned u = __float_as_uint(f);
    unsigned r = u + 0x7fff + ((u >> 16) & 1);
    return (unsigned short)(r >> 16);
}
DEVINL float bf2f(unsigned short h) { return __uint_as_float(((unsigned)h) << 16); }

// unpack 2 bf16 (packed in one u32) -> f32x2
DEVINL f32x2 bf2f2(unsigned u) {
    f32x2 r;
    r.x = __uint_as_float(u << 16);
    r.y = __uint_as_float(u & 0xffff0000u);
    return r;
}

// VALU-only 16-lane-row rotate-add step (DPP row_ror:N); 4 steps => row sum in all 16 lanes
template <int CTRL>
DEVINL float dppadd(float x) {
    return x + __int_as_float(__builtin_amdgcn_update_dpp(
        0, __float_as_int(x), CTRL, 0xF, 0xF, false));
}
DEVINL float rowsum16(float x) {
    x = dppadd<0x121>(x);   // row_ror:1
    x = dppadd<0x122>(x);   // row_ror:2
    x = dppadd<0x124>(x);   // row_ror:4
    x = dppadd<0x128>(x);   // row_ror:8
    return x;
}

DEVINL void gload_lds16(const void* g, void* l) {
    __builtin_amdgcn_global_load_lds(
        (const __attribute__((address_space(1))) void*)g,
        (__attribute__((address_space(3))) void*)l, 16, 0, 0);
}

// ---------------- CSR build ----------------

__global__ void build_edges(const int* __restrict__ ei, int E, int N,
                            int* __restrict__ src, int* __restrict__ dst,
                            int* __restrict__ counts) {
    int e = blockIdx.x * 256 + threadIdx.x;
    int ET = E + N;
    if (e >= ET) return;
    int s, d;
    if (e < E) { s = ei[e]; d = ei[E + e]; }
    else       { s = d = e - E; }
    s = min(max(s, 0), N - 1);
    d = min(max(d, 0), N - 1);
    src[e] = s;
    dst[e] = d;
    atomicAdd(&counts[d], 1);
}

__global__ void scan_offsets(const int* __restrict__ counts, int* __restrict__ offsets, int N) {
    const int T = 1024;
    __shared__ int sums[T];
    int t = threadIdx.x;
    int chunk = (N + T - 1) / T;
    int base = t * chunk;
    int local[16];
    int s = 0;
    for (int i = 0; i < chunk; ++i) {
        int v = (base + i < N) ? counts[base + i] : 0;
        local[i] = s;
        s += v;
    }
    sums[t] = s;
    __syncthreads();
    for (int d = 1; d < T; d <<= 1) {
        int v = (t >= d) ? sums[t - d] : 0;
        __syncthreads();
        sums[t] += v;
        __syncthreads();
    }
    int excl = (t == 0) ? 0 : sums[t - 1];
    for (int i = 0; i < chunk; ++i)
        if (base + i < N) offsets[base + i] = excl + local[i];
    if (t == T - 1) offsets[N] = excl + s;
}

__global__ void fill_eids(const int* __restrict__ src, const int* __restrict__ dst,
                          const int* __restrict__ offsets,
                          int* __restrict__ cursor, int* __restrict__ esrc, int ET) {
    int e = blockIdx.x * 256 + threadIdx.x;
    if (e >= ET) return;
    int d = dst[e];
    int pos = offsets[d] + atomicAdd(&cursor[d], 1);
    esrc[pos] = src[e];
}

// ---------------- f32 -> hi bf16 (RNE), zero-padded rows >= M ----------------
__global__ void conv_hi(const float* __restrict__ x, unsigned short* __restrict__ hi,
                        int M, int log2K, int total4) {
    int i = blockIdx.x * 256 + threadIdx.x;
    if (i >= total4) return;
    int e = i * 4;
    int row = e >> log2K;
    ushort4 vh = make_ushort4(0, 0, 0, 0);
    if (row < M) {
        float4 v = *(const float4*)&x[e];
        vh = make_ushort4(f2bf_rne(v.x), f2bf_rne(v.y), f2bf_rne(v.z), f2bf_rne(v.w));
    }
    *(ushort4*)&hi[e] = vh;
}

// ---------------- W[K][Nout] f32 -> BT[Nout][K] hi bf16; blockIdx.z picks W0/W1 ----------------
__global__ void thi2(const float* __restrict__ W0, const float* __restrict__ W1,
                     unsigned short* __restrict__ BT, int K, int Nout) {
    __shared__ float tile[32][33];
    const float* W = blockIdx.z ? W1 : W0;
    unsigned short* out = BT + (size_t)blockIdx.z * Nout * K;
    int n0 = blockIdx.x * 32, k0 = blockIdx.y * 32;
    int tx = threadIdx.x, ty = threadIdx.y;
#pragma unroll
    for (int i = 0; i < 4; ++i)
        tile[ty + 8 * i][tx] = W[(size_t)(k0 + ty + 8 * i) * Nout + n0 + tx];
    __syncthreads();
#pragma unroll
    for (int i = 0; i < 4; ++i) {
        int r = ty + 8 * i;
        out[(size_t)(n0 + r) * K + k0 + tx] = f2bf_rne(tile[tx][r]);
    }
}

// ---------------- bf16 MFMA GEMM: C[M][Nout] = A[M2][K] @ BT[Nout][K]^T ----------------
// 128x128 tile, BK=64, 4 waves (2x2), 16x16x32 bf16 MFMA, T1 bijective XCD swizzle.
template <int TERMS, bool OUTBF16>
__global__ __launch_bounds__(256) void gemm_mfma(
    const unsigned short* __restrict__ Ah, const unsigned short* __restrict__ Al,
    const unsigned short* __restrict__ Bh,
    float* __restrict__ Cf, unsigned short* __restrict__ Cb,
    int M, int Nout, int K) {
    constexpr int BOFF = (TERMS == 2) ? 32768 : 16384;
    __shared__ __align__(16) char lds[BOFF + 16384];
    const int t = threadIdx.x;
    const int L = t & 63, w = t >> 6;
    const int wm = w & 1, wn = w >> 1;
    const int nwg = gridDim.x * gridDim.y;
    int orig = blockIdx.y * gridDim.x + blockIdx.x;
    int q = nwg >> 3, rr = nwg & 7;
    int xcd = orig & 7, pos = orig >> 3;
    int wg = (xcd < rr ? xcd * (q + 1) : rr * (q + 1) + (xcd - rr) * q) + pos;
    const int bm = (wg / gridDim.x) * 128, bn = (wg % gridDim.x) * 128;
    const size_t strideA = (size_t)K * 2;

    const f32x4 vzero = {0.f, 0.f, 0.f, 0.f};
    f32x4 acc[4][4];
#pragma unroll
    for (int i = 0; i < 4; ++i)
#pragma unroll
        for (int j = 0; j < 4; ++j) acc[i][j] = vzero;

    for (int k0 = 0; k0 < K; k0 += 64) {
#pragma unroll
        for (int i = 0; i < 4; ++i) {
            int slot = i * 256 + t;
            int offs = slot * 16;
            int r = offs >> 7;
            int cb = (offs & 127) ^ ((r & 7) << 4);
            size_t gofs = (size_t)r * strideA + (size_t)k0 * 2 + cb;
            gload_lds16((const char*)Ah + (size_t)bm * strideA + gofs, lds + offs);
            if constexpr (TERMS == 2)
                gload_lds16((const char*)Al + (size_t)bm * strideA + gofs, lds + 16384 + offs);
            gload_lds16((const char*)Bh + (size_t)bn * strideA + gofs, lds + BOFF + offs);
        }
        __syncthreads();
#pragma unroll
        for (int kf = 0; kf < 2; ++kf) {
            const int kb = kf * 64 + ((L >> 4) * 16);
            bf16x8 ah[4], al[4], bh[4];
#pragma unroll
            for (int mi = 0; mi < 4; ++mi) {
                int r = wm * 64 + mi * 16 + (L & 15);
                int off = r * 128 + (kb ^ ((r & 7) << 4));
                ah[mi] = *(const bf16x8*)(lds + off);
                if constexpr (TERMS == 2) al[mi] = *(const bf16x8*)(lds + 16384 + off);
            }
#pragma unroll
            for (int ni = 0; ni < 4; ++ni) {
                int r = wn * 64 + ni * 16 + (L & 15);
                int off = r * 128 + (kb ^ ((r & 7) << 4));
                bh[ni] = *(const bf16x8*)(lds + BOFF + off);
            }
#pragma unroll
            for (int mi = 0; mi < 4; ++mi)
#pragma unroll
                for (int ni = 0; ni < 4; ++ni) {
                    acc[mi][ni] = __builtin_amdgcn_mfma_f32_16x16x32_bf16(ah[mi], bh[ni], acc[mi][ni], 0, 0, 0);
                    if constexpr (TERMS == 2)
                        acc[mi][ni] = __builtin_amdgcn_mfma_f32_16x16x32_bf16(al[mi], bh[ni], acc[mi][ni], 0, 0, 0);
                }
        }
        __syncthreads();
    }
    const int colBase = bn + wn * 64 + (L & 15);
#pragma unroll
    for (int mi = 0; mi < 4; ++mi) {
        int row0 = bm + wm * 64 + mi * 16 + (L >> 4) * 4;
#pragma unroll
        for (int j = 0; j < 4; ++j) {
            int row = row0 + j;
            if (row < M) {
#pragma unroll
                for (int ni = 0; ni < 4; ++ni) {
                    if constexpr (OUTBF16)
                        Cb[(size_t)row * Nout + colBase + ni * 16] = f2bf_rne(acc[mi][ni][j]);
                    else
                        Cf[(size_t)row * Nout + colBase + ni * 16] = acc[mi][ni][j];
                }
            }
        }
    }
}

// ---------------- layer-1 fused aggregate: 256-thread block = 2 nodes ----------------
// Per node: 2 waves; wave wv covers heads 2wv,2wv+1 (contiguous 1KB per gather,
// 16B/lane). Edge indices scalarized (SGPR base). 4 edges in flight per
// iteration (4 independent gather+DPP-reduce+exp chains hide L2/L3 latency);
// tail edges clamp the index and zero the weight (no divergence).
__global__ __launch_bounds__(256) void agg1(const unsigned short* __restrict__ xlr,  // [M2][2048]
                                            const float* __restrict__ att,           // [4][256]
                                            const int* __restrict__ offsets,
                                            const int* __restrict__ esrc,
                                            const float* __restrict__ bias,          // [256]
                                            unsigned short* __restrict__ outH,
                                            unsigned short* __restrict__ outL,
                                            int N) {
    __shared__ float accLds[2][4][256];
    const int t = threadIdx.x;
    const int half = t >> 7;             // node slot within block
    const int ht = t & 127;
    const int wv = ht >> 6, lane = ht & 63;
    const int n = blockIdx.x * 2 + half;

    if (blockIdx.x * 2 >= N) {           // all-pad block (N even -> boundary aligned)
        int c = ht * 2;
        *(ushort2*)&outH[(size_t)n * 256 + c] = make_ushort2(0, 0);
        *(ushort2*)&outL[(size_t)n * 256 + c] = make_ushort2(0, 0);
        return;
    }

    const int eoff = 512 * wv + lane * 8;   // element offset in xl row [0,1024)
    const int h = eoff >> 8;                // head 0..3
    const int gl = lane & 31;

    f32x2 a2[4], r2[4];
    {
        const float* pa = att + h * 256 + gl * 8;
#pragma unroll
        for (int p = 0; p < 4; ++p) { a2[p].x = pa[2 * p]; a2[p].y = pa[2 * p + 1]; }
        const uint4 u = *(const uint4*)(xlr + (size_t)n * 2048 + 1024 + eoff);
        r2[0] = bf2f2(u.x); r2[1] = bf2f2(u.y); r2[2] = bf2f2(u.z); r2[3] = bf2f2(u.w);
    }
    const int o0  = __builtin_amdgcn_readfirstlane(offsets[n]);
    const int deg = __builtin_amdgcn_readfirstlane(offsets[n + 1]) - o0;

    f32x2 acc2[4];
#pragma unroll
    for (int p = 0; p < 4; ++p) acc2[p] = (f32x2){0.f, 0.f};
    float s = 0.f;

    for (int j = 0; j < deg; j += 4) {
        // 4 independent gathers in flight (indices clamped; tail weights zeroed)
        uint4 g[4];
#pragma unroll
        for (int k = 0; k < 4; ++k) {
            int idx = min(j + k, deg - 1);
            int e = __builtin_amdgcn_readfirstlane(esrc[o0 + idx]);
            g[k] = *(const uint4*)(xlr + (size_t)e * 2048 + eoff);
        }
        f32x2 xk[4][4];
        float q[4];
#pragma unroll
        for (int k = 0; k < 4; ++k) {
            xk[k][0] = bf2f2(g[k].x); xk[k][1] = bf2f2(g[k].y);
            xk[k][2] = bf2f2(g[k].z); xk[k][3] = bf2f2(g[k].w);
            f32x2 qp = {0.f, 0.f};
#pragma unroll
            for (int p = 0; p < 4; ++p) {
                f32x2 tv = xk[k][p] + r2[p];
                f32x2 mv = tv * 0.2f;
                f32x2 uv;
                uv.x = fmaxf(tv.x, mv.x);
                uv.y = fmaxf(tv.y, mv.y);
                qp += a2[p] * uv;
            }
            q[k] = qp.x + qp.y;
        }
#pragma unroll
        for (int k = 0; k < 4; ++k) {
            q[k] = rowsum16(q[k]);
            q[k] += __shfl_xor(q[k], 16);
            q[k] = fminf(fmaxf(q[k], -60.f), 60.f);
        }
#pragma unroll
        for (int k = 0; k < 4; ++k) {
            float wk = (j + k < deg) ? __expf(q[k]) : 0.f;
            s += wk;
            f32x2 w2 = {wk, wk};
#pragma unroll
            for (int p = 0; p < 4; ++p) acc2[p] += xk[k][p] * w2;
        }
    }

    float inv = 1.0f / s;   // uniform within 32-lane half
    {
        float* dst = &accLds[half][h][gl * 8];
#pragma unroll
        for (int p = 0; p < 4; ++p) {
            dst[2 * p]     = acc2[p].x * inv;
            dst[2 * p + 1] = acc2[p].y * inv;
        }
    }
    __syncthreads();

    {   // head-mean + bias + lrelu + hi/lo split; thread owns channels 2ht, 2ht+1 of its node
        int c = ht * 2;
        float v0 = (accLds[half][0][c] + accLds[half][1][c] + accLds[half][2][c] + accLds[half][3][c]) * 0.25f + bias[c];
        float v1 = (accLds[half][0][c + 1] + accLds[half][1][c + 1] + accLds[half][2][c + 1] + accLds[half][3][c + 1]) * 0.25f + bias[c + 1];
        v0 = lrelu(v0); v1 = lrelu(v1);
        unsigned short h0 = f2bf_rne(v0), h1v = f2bf_rne(v1);
        *(ushort2*)&outH[(size_t)n * 256 + c] = make_ushort2(h0, h1v);
        *(ushort2*)&outL[(size_t)n * 256 + c] =
            make_ushort2(f2bf_rne(v0 - bf2f(h0)), f2bf_rne(v1 - bf2f(h1v)));
    }
}

// ---------------- layer-2 fused aggregate: one wave per node ----------------
// 64 lanes cover the whole 1KB row (16-lane group per head == DPP row).
// 4 edges in flight; reduce = 4 DPP adds (pure VALU). Head-mean via shfl 16/32.
__global__ __launch_bounds__(256) void agg2(const unsigned short* __restrict__ xlr,  // [N][1024]
                                            const float* __restrict__ att,           // [4][128]
                                            const int* __restrict__ offsets,
                                            const int* __restrict__ esrc,
                                            const float* __restrict__ bias,          // [128]
                                            float* __restrict__ out, int N) {
    const int lane = threadIdx.x & 63;
    const int n = blockIdx.x * 4 + (threadIdx.x >> 6);
    if (n >= N) return;
    const int h = lane >> 4, gl = lane & 15;
    const int eoff = lane * 8;

    f32x2 a2[4], bs2[4], r2[4];
    {
        const float* pa = att + h * 128 + gl * 8;
        const float* pb = bias + gl * 8;
#pragma unroll
        for (int p = 0; p < 4; ++p) {
            a2[p].x = pa[2 * p];  a2[p].y = pa[2 * p + 1];
            bs2[p].x = pb[2 * p]; bs2[p].y = pb[2 * p + 1];
        }
        const uint4 u = *(const uint4*)(xlr + (size_t)n * 1024 + 512 + eoff);
        r2[0] = bf2f2(u.x); r2[1] = bf2f2(u.y); r2[2] = bf2f2(u.z); r2[3] = bf2f2(u.w);
    }
    const int o0  = __builtin_amdgcn_readfirstlane(offsets[n]);
    const int deg = __builtin_amdgcn_readfirstlane(offsets[n + 1]) - o0;

    f32x2 acc2[4];
#pragma unroll
    for (int p = 0; p < 4; ++p) acc2[p] = (f32x2){0.f, 0.f};
    float s = 0.f;

    for (int j = 0; j < deg; j += 4) {
        uint4 g[4];
#pragma unroll
        for (int k = 0; k < 4; ++k) {
            int idx = min(j + k, deg - 1);
            int e = __builtin_amdgcn_readfirstlane(esrc[o0 + idx]);
            g[k] = *(const uint4*)(xlr + (size_t)e * 1024 + eoff);
        }
        f32x2 xk[4][4];
        float q[4];
#pragma unroll
        for (int k = 0; k < 4; ++k) {
            xk[k][0] = bf2f2(g[k].x); xk[k][1] = bf2f2(g[k].y);
            xk[k][2] = bf2f2(g[k].z); xk[k][3] = bf2f2(g[k].w);
            f32x2 qp = {0.f, 0.f};
#pragma unroll
            for (int p = 0; p < 4; ++p) {
                f32x2 tv = xk[k][p] + r2[p];
                f32x2 mv = tv * 0.2f;
                f32x2 uv;
                uv.x = fmaxf(tv.x, mv.x);
                uv.y = fmaxf(tv.y, mv.y);
                qp += a2[p] * uv;
            }
            q[k] = qp.x + qp.y;
        }
#pragma unroll
        for (int k = 0; k < 4; ++k) {
            q[k] = rowsum16(q[k]);   // head group == DPP row
            q[k] = fminf(fmaxf(q[k], -60.f), 60.f);
        }
#pragma unroll
        for (int k = 0; k < 4; ++k) {
            float wk = (j + k < deg) ? __expf(q[k]) : 0.f;
            s += wk;
            f32x2 w2 = {wk, wk};
#pragma unroll
            for (int p = 0; p < 4; ++p) acc2[p] += xk[k][p] * w2;
        }
    }

    float inv = 1.0f / s;
#pragma unroll
    for (int p = 0; p < 4; ++p) {
        acc2[p].x *= inv; acc2[p].y *= inv;
        acc2[p].x += __shfl_xor(acc2[p].x, 16);
        acc2[p].x += __shfl_xor(acc2[p].x, 32);
        acc2[p].y += __shfl_xor(acc2[p].y, 16);
        acc2[p].y += __shfl_xor(acc2[p].y, 32);
    }
    if (h == 0) {
        float o[8];
#pragma unroll
        for (int p = 0; p < 4; ++p) {
            o[2 * p]     = tanhf(acc2[p].x * 0.25f + bs2[p].x);
            o[2 * p + 1] = tanhf(acc2[p].y * 0.25f + bs2[p].y);
        }
        float* po = out + (size_t)n * 128 + gl * 8;
        *(float4*)po = make_float4(o[0], o[1], o[2], o[3]);
        *(float4*)(po + 4) = make_float4(o[4], o[5], o[6], o[7]);
    }
}

// ---------------- launch ----------------

extern "C" void kernel_launch(void* const* d_in, const int* in_sizes, int n_in,
                              void* d_out, int out_size, void* d_ws, size_t ws_size,
                              hipStream_t stream) {
    const float* x    = (const float*)d_in[0];
    const int*   ei   = (const int*)d_in[1];
    const float* Wl1  = (const float*)d_in[2];
    const float* Wr1  = (const float*)d_in[3];
    const float* att1 = (const float*)d_in[4];
    const float* b1   = (const float*)d_in[5];
    const float* Wl2  = (const float*)d_in[6];
    const float* Wr2  = (const float*)d_in[7];
    const float* att2 = (const float*)d_in[8];
    const float* b2   = (const float*)d_in[9];
    float* out = (float*)d_out;

    const int IN = 512, HID = 256, OUT = 128, H = 4;
    int N  = in_sizes[0] / IN;
    int E  = in_sizes[1] / 2;
    int ET = E + N;
    int M2 = ((N + 127) / 128) * 128;   // 10112

    char* w = (char*)d_ws;
    auto carve = [&](size_t bytes) {
        char* p = w;
        w += (bytes + 255) & ~(size_t)255;
        return (void*)p;
    };
    unsigned short* x_hi = (unsigned short*)carve((size_t)M2 * IN * 2);
    unsigned short* xlr1 = (unsigned short*)carve((size_t)N * 2 * H * HID * 2);
    unsigned short* BT1 = (unsigned short*)carve((size_t)(2 * H * HID) * IN * 2);
    int* src     = (int*)carve((size_t)ET * 4);
    int* dst     = (int*)carve((size_t)ET * 4);
    int* counts  = (int*)carve((size_t)N * 4);
    int* cursor  = (int*)carve((size_t)N * 4);
    int* offsets = (int*)carve((size_t)(N + 1) * 4);
    int* esrc    = (int*)carve((size_t)ET * 4);
    unsigned short* h1_h = x_hi;
    unsigned short* h1_l = x_hi + (size_t)M2 * HID;
    unsigned short* xlr2 = xlr1;
    unsigned short* BT2  = BT1;

    // ---- CSR build ----
    hipMemsetAsync(counts, 0, (size_t)((char*)offsets - (char*)counts), stream);
    build_edges<<<(ET + 255) / 256, 256, 0, stream>>>(ei, E, N, src, dst, counts);
    scan_offsets<<<1, 1024, 0, stream>>>(counts, offsets, N);
    fill_eids<<<(ET + 255) / 256, 256, 0, stream>>>(src, dst, offsets, cursor, esrc, ET);

    // ---- prep layer 1 ----
    {
        int total4 = M2 * IN / 4;
        conv_hi<<<(total4 + 255) / 256, 256, 0, stream>>>(x, x_hi, N, 9, total4);
        thi2<<<dim3((H * HID) / 32, IN / 32, 2), dim3(32, 8), 0, stream>>>(Wl1, Wr1, BT1, IN, H * HID);
    }
    // ---- layer 1 GEMM (combined Wl|Wr, pure bf16, bf16 out) ----
    {
        dim3 g((2 * H * HID) / 128, M2 / 128);
        gemm_mfma<1, true><<<g, 256, 0, stream>>>(x_hi, nullptr, BT1, nullptr, xlr1, N, 2 * H * HID, IN);
    }
    // ---- layer 1 aggregate: 2 nodes per block, 4 edges in flight ----
    agg1<<<M2 / 2, 256, 0, stream>>>(xlr1, att1, offsets, esrc, b1, h1_h, h1_l, N);
    // ---- prep layer 2 ----
    thi2<<<dim3((H * OUT) / 32, HID / 32, 2), dim3(32, 8), 0, stream>>>(Wl2, Wr2, BT2, HID, H * OUT);
    // ---- layer 2 GEMM (combined, 2-term, bf16 out) ----
    {
        dim3 g((2 * H * OUT) / 128, M2 / 128);
        gemm_mfma<2, true><<<g, 256, 0, stream>>>(h1_h, h1_l, BT2, nullptr, xlr2, N, 2 * H * OUT, HID);
    }
    // ---- layer 2 aggregate: wave per node, 4 edges in flight ----
    agg2<<<(N + 3) / 4, 256, 0, stream>>>(xlr2, att2, offsets, esrc, b2, out, N);
}